// Round 7
// baseline (1533.170 us; speedup 1.0000x reference)
//
#include <hip/hip_runtime.h>
#include <hip/hip_bf16.h>

#define WAVE 64

typedef __attribute__((ext_vector_type(8))) short short8;
typedef __attribute__((ext_vector_type(4))) float f32x4;

__device__ __forceinline__ unsigned short f32_to_bf16_rne(float f) {
    unsigned int u = __float_as_uint(f);
    u = u + 0x7fffu + ((u >> 16) & 1u);   // round-to-nearest-even
    return (unsigned short)(u >> 16);
}
__device__ __forceinline__ float bf16_to_f32(unsigned short h) {
    return __uint_as_float((unsigned int)h << 16);
}

// ---------------------------------------------------------------------------
// CSR build: histogram -> exclusive scan (single block) -> scatter fill
// ---------------------------------------------------------------------------
__global__ void hist_kernel(const int* __restrict__ dst, int E, int* __restrict__ cnt) {
    int e = blockIdx.x * blockDim.x + threadIdx.x;
    if (e < E) atomicAdd(&cnt[dst[e]], 1);
}

__global__ __launch_bounds__(1024) void exscan_kernel(const int* __restrict__ cnt,
                                                      int* __restrict__ off, int N) {
    __shared__ int part[1024];
    int t = threadIdx.x;
    int chunk = (N + 1023) / 1024;
    int lo = t * chunk;
    int hi = lo + chunk; if (hi > N) hi = N;
    int s = 0;
    for (int i = lo; i < hi; ++i) s += cnt[i];
    part[t] = s;
    __syncthreads();
    for (int o = 1; o < 1024; o <<= 1) {
        int v = (t >= o) ? part[t - o] : 0;
        __syncthreads();
        part[t] += v;
        __syncthreads();
    }
    int run = (t == 0) ? 0 : part[t - 1];
    for (int i = lo; i < hi; ++i) { off[i] = run; run += cnt[i]; }
    if (t == 1023) off[N] = part[1023];
}

__global__ void fill_kernel(const int* __restrict__ src, const int* __restrict__ dst, int E,
                            const int* __restrict__ off, int* __restrict__ cursor,
                            int* __restrict__ csr_src) {
    int e = blockIdx.x * blockDim.x + threadIdx.x;
    if (e < E) {
        int d = dst[e];
        int pos = off[d] + atomicAdd(&cursor[d], 1);
        csr_src[pos] = src[e];
    }
}

// ---------------------------------------------------------------------------
// fp32 -> bf16 convert (4 elems/thread)
// ---------------------------------------------------------------------------
__global__ void cvt_bf16_kernel(const float* __restrict__ in, unsigned short* __restrict__ out,
                                int n4) {
    int i = blockIdx.x * blockDim.x + threadIdx.x;
    if (i >= n4) return;
    float4 v = *(const float4*)(in + (size_t)i * 4);
    ushort4 o;
    o.x = f32_to_bf16_rne(v.x);
    o.y = f32_to_bf16_rne(v.y);
    o.z = f32_to_bf16_rne(v.z);
    o.w = f32_to_bf16_rne(v.w);
    *(ushort4*)(out + (size_t)i * 4) = o;
}

// W [K][N] fp32 -> WT [N][K] bf16
__global__ void wt_bf16_kernel(const float* __restrict__ W, unsigned short* __restrict__ WT,
                               int K, int N) {
    int idx = blockIdx.x * blockDim.x + threadIdx.x;
    if (idx >= K * N) return;
    int k = idx / N, n = idx - k * N;
    WT[(size_t)n * K + k] = f32_to_bf16_rne(W[idx]);
}

// ---------------------------------------------------------------------------
// rowdot fp32: out[n] = dot(X[n, 0:F], v[0:F])   (one wave per row)
// ---------------------------------------------------------------------------
__global__ void rowdot_kernel(const float* __restrict__ X, const float* __restrict__ v,
                              float* __restrict__ out, int N, int F) {
    int w = (blockIdx.x * blockDim.x + threadIdx.x) >> 6;
    int lane = threadIdx.x & 63;
    if (w >= N) return;
    const float* row = X + (size_t)w * F;
    float s = 0.f;
    for (int f = lane; f < F; f += WAVE) s += row[f] * v[f];
    #pragma unroll
    for (int o = 32; o; o >>= 1) s += __shfl_xor(s, o);
    if (lane == 0) out[w] = s;
}

// rowdot bf16 X, fp32 v
__global__ void rowdot_bf16(const unsigned short* __restrict__ X, const float* __restrict__ v,
                            float* __restrict__ out, int N, int F) {
    int w = (blockIdx.x * blockDim.x + threadIdx.x) >> 6;
    int lane = threadIdx.x & 63;
    if (w >= N) return;
    const unsigned short* row = X + (size_t)w * F;
    float s = 0.f;
    for (int f = lane; f < F; f += WAVE) s += bf16_to_f32(row[f]) * v[f];
    #pragma unroll
    for (int o = 32; o; o >>= 1) s += __shfl_xor(s, o);
    if (lane == 0) out[w] = s;
}

// ---------------------------------------------------------------------------
// bf16 MFMA GEMM: C[M,N] = A[M,K] @ BT[N,K]^T.  A,BT bf16; C bf16.
// Tile 128x64, 4 waves (2x2), BK=64, mfma_f32_16x16x32_bf16.
// Requires K % 64 == 0, N % 64 == 0.
// ---------------------------------------------------------------------------
#define GBM 128
#define GBN 64
#define GBK 64
#define LDP (GBK + 8)   // +8 bf16 pad: row stride 144B (9x16B) -> <=2-way conflict

__global__ __launch_bounds__(256) void gemm_bf16(const unsigned short* __restrict__ A,
                                                 const unsigned short* __restrict__ BT,
                                                 unsigned short* __restrict__ C,
                                                 int M, int N, int K) {
    __shared__ unsigned short As[GBM][LDP];
    __shared__ unsigned short Bs[GBN][LDP];

    int tid  = threadIdx.x;
    int lane = tid & 63;
    int wid  = tid >> 6;
    int wr   = wid >> 1;          // 0..1 : M-half (64 rows)
    int wc   = wid & 1;           // 0..1 : N-half (32 cols)
    int ln   = lane & 15;
    int hi   = lane >> 4;         // 0..3

    int row0 = blockIdx.x * GBM;
    int col0 = blockIdx.y * GBN;

    int sr = tid >> 3;            // 0..31 staging row within pass
    int sk = (tid & 7) << 3;      // k-offset (8 bf16 = 16B)

    f32x4 acc[4][2];
    #pragma unroll
    for (int i = 0; i < 4; ++i)
        #pragma unroll
        for (int j = 0; j < 2; ++j)
            acc[i][j] = (f32x4){0.f, 0.f, 0.f, 0.f};

    for (int k0 = 0; k0 < K; k0 += GBK) {
        #pragma unroll
        for (int p = 0; p < 4; ++p) {
            int r = sr + p * 32;
            int gr = row0 + r;
            short8 v = (short8){0,0,0,0,0,0,0,0};
            if (gr < M)
                v = *(const short8*)(A + (size_t)gr * K + k0 + sk);
            *(short8*)&As[r][sk] = v;
        }
        #pragma unroll
        for (int p = 0; p < 2; ++p) {
            int r = sr + p * 32;
            short8 v = *(const short8*)(BT + (size_t)(col0 + r) * K + k0 + sk);
            *(short8*)&Bs[r][sk] = v;
        }
        __syncthreads();

        #pragma unroll
        for (int kk = 0; kk < 2; ++kk) {
            short8 a[4], b[2];
            #pragma unroll
            for (int mi = 0; mi < 4; ++mi)
                a[mi] = *(const short8*)&As[wr * 64 + mi * 16 + ln][kk * 32 + hi * 8];
            #pragma unroll
            for (int ni = 0; ni < 2; ++ni)
                b[ni] = *(const short8*)&Bs[wc * 32 + ni * 16 + ln][kk * 32 + hi * 8];
            #pragma unroll
            for (int mi = 0; mi < 4; ++mi)
                #pragma unroll
                for (int ni = 0; ni < 2; ++ni)
                    acc[mi][ni] = __builtin_amdgcn_mfma_f32_16x16x32_bf16(
                        a[mi], b[ni], acc[mi][ni], 0, 0, 0);
        }
        __syncthreads();
    }

    // C/D layout (verified m89/m91): col = lane&15, row = (lane>>4)*4 + reg
    #pragma unroll
    for (int mi = 0; mi < 4; ++mi) {
        #pragma unroll
        for (int ni = 0; ni < 2; ++ni) {
            int gcol = col0 + wc * 32 + ni * 16 + ln;
            #pragma unroll
            for (int r = 0; r < 4; ++r) {
                int grow = row0 + wr * 64 + mi * 16 + hi * 4 + r;
                if (grow < M) C[(size_t)grow * N + gcol] = f32_to_bf16_rne(acc[mi][ni][r]);
            }
        }
    }
}

// ---------------------------------------------------------------------------
// Final-layer GEMM: C[M,16] = A[M,256](bf16) @ B[256,16](fp32).  One wave/row.
// lane = n + 16*kg ; each lane sums 64 k values, reduce across 4 k-groups.
// ---------------------------------------------------------------------------
__global__ __launch_bounds__(256) void gemm_bf16_n16(const unsigned short* __restrict__ A,
                                                     const float* __restrict__ B,
                                                     float* __restrict__ C, int M) {
    int w = (blockIdx.x * blockDim.x + threadIdx.x) >> 6;
    int lane = threadIdx.x & 63;
    if (w >= M) return;
    int n = lane & 15, kg = lane >> 4;
    const unsigned short* row = A + (size_t)w * 256 + kg * 64;
    const float* Bp = B + (size_t)kg * 64 * 16 + n;
    float s = 0.f;
    #pragma unroll 8
    for (int j = 0; j < 64; ++j)
        s += bf16_to_f32(row[j]) * Bp[(size_t)j * 16];
    s += __shfl_xor(s, 16);
    s += __shfl_xor(s, 32);
    if (lane < 16) C[(size_t)w * 16 + n] = s;
}

// ---------------------------------------------------------------------------
// GAT softmax + aggregation, Fout=256, bf16 H in / bf16 out. One wave per dst.
// ---------------------------------------------------------------------------
template <bool RELU>
__global__ __launch_bounds__(256) void gat_agg256(
        const unsigned short* __restrict__ H, const float* __restrict__ ssrc,
        const float* __restrict__ sdst, const int* __restrict__ off,
        const int* __restrict__ csr, const float* __restrict__ bias,
        unsigned short* __restrict__ out, int Nd) {
    int wid = (blockIdx.x * blockDim.x + threadIdx.x) >> 6;
    int lane = threadIdx.x & 63;
    if (wid >= Nd) return;
    int s0 = off[wid], s1 = off[wid + 1];
    float sd = sdst[wid];

    float mx = -1e30f;
    for (int i = s0 + lane; i < s1; i += WAVE) {
        float l = ssrc[csr[i]] + sd;
        l = (l > 0.f) ? l : 0.2f * l;
        mx = fmaxf(mx, l);
    }
    #pragma unroll
    for (int o = 32; o; o >>= 1) mx = fmaxf(mx, __shfl_xor(mx, o));
    float m = (s1 > s0) ? mx : 0.f;

    float sum = 0.f;
    for (int i = s0 + lane; i < s1; i += WAVE) {
        float l = ssrc[csr[i]] + sd;
        l = (l > 0.f) ? l : 0.2f * l;
        sum += __expf(l - m);
    }
    #pragma unroll
    for (int o = 32; o; o >>= 1) sum += __shfl_xor(sum, o);
    float inv = 1.f / (sum + 1e-16f);

    float4 acc = make_float4(0.f, 0.f, 0.f, 0.f);
    for (int i = s0; i < s1; ++i) {
        int s = csr[i];
        float l = ssrc[s] + sd;
        l = (l > 0.f) ? l : 0.2f * l;
        float w = __expf(l - m);
        ushort4 hv = *(const ushort4*)(H + (size_t)s * 256 + (lane << 2));
        acc.x += w * bf16_to_f32(hv.x);
        acc.y += w * bf16_to_f32(hv.y);
        acc.z += w * bf16_to_f32(hv.z);
        acc.w += w * bf16_to_f32(hv.w);
    }
    float4 bv = *(const float4*)(bias + (lane << 2));
    float4 o4;
    o4.x = acc.x * inv + bv.x;
    o4.y = acc.y * inv + bv.y;
    o4.z = acc.z * inv + bv.z;
    o4.w = acc.w * inv + bv.w;
    if (RELU) {
        o4.x = fmaxf(o4.x, 0.f); o4.y = fmaxf(o4.y, 0.f);
        o4.z = fmaxf(o4.z, 0.f); o4.w = fmaxf(o4.w, 0.f);
    }
    ushort4 ov;
    ov.x = f32_to_bf16_rne(o4.x);
    ov.y = f32_to_bf16_rne(o4.y);
    ov.z = f32_to_bf16_rne(o4.z);
    ov.w = f32_to_bf16_rne(o4.w);
    *(ushort4*)(out + (size_t)wid * 256 + (lane << 2)) = ov;
}

// Fout=16, fp32 H in / fp32 out (final layer, no relu). One wave per dst.
__global__ __launch_bounds__(256) void gat_agg16(
        const float* __restrict__ H, const float* __restrict__ ssrc,
        const float* __restrict__ sdst, const int* __restrict__ off,
        const int* __restrict__ csr, const float* __restrict__ bias,
        float* __restrict__ out, int Nd) {
    int wid = (blockIdx.x * blockDim.x + threadIdx.x) >> 6;
    int lane = threadIdx.x & 63;
    if (wid >= Nd) return;
    int s0 = off[wid], s1 = off[wid + 1];
    float sd = sdst[wid];

    float mx = -1e30f;
    for (int i = s0 + lane; i < s1; i += WAVE) {
        float l = ssrc[csr[i]] + sd;
        l = (l > 0.f) ? l : 0.2f * l;
        mx = fmaxf(mx, l);
    }
    #pragma unroll
    for (int o = 32; o; o >>= 1) mx = fmaxf(mx, __shfl_xor(mx, o));
    float m = (s1 > s0) ? mx : 0.f;

    float sum = 0.f;
    for (int i = s0 + lane; i < s1; i += WAVE) {
        float l = ssrc[csr[i]] + sd;
        l = (l > 0.f) ? l : 0.2f * l;
        sum += __expf(l - m);
    }
    #pragma unroll
    for (int o = 32; o; o >>= 1) sum += __shfl_xor(sum, o);
    float inv = 1.f / (sum + 1e-16f);

    float acc = 0.f;
    for (int i = s0; i < s1; ++i) {
        int s = csr[i];
        float l = ssrc[s] + sd;
        l = (l > 0.f) ? l : 0.2f * l;
        float w = __expf(l - m);
        if (lane < 16) acc += w * H[(size_t)s * 16 + lane];
    }
    if (lane < 16)
        out[(size_t)wid * 16 + lane] = acc * inv + bias[lane];
}

// ---------------------------------------------------------------------------
// Epilogue
// ---------------------------------------------------------------------------
__global__ void sum_rows16(const float* __restrict__ X, const int* __restrict__ idx,
                           int L, float* __restrict__ accum) {
    __shared__ float red[16][16];
    int f = threadIdx.x & 15, r = threadIdx.x >> 4;
    float acc = 0.f;
    for (int i = blockIdx.x * 16 + r; i < L; i += gridDim.x * 16)
        acc += X[(size_t)idx[i] * 16 + f];
    red[r][f] = acc;
    __syncthreads();
    #pragma unroll
    for (int o = 8; o; o >>= 1) {
        if (r < o) red[r][f] += red[r + o][f];
        __syncthreads();
    }
    if (r == 0) atomicAdd(&accum[f], red[0][f]);
}

__global__ void pred16(const float* __restrict__ XA, const int* __restrict__ sidx,
                       const float* __restrict__ accum, float* __restrict__ pred, int L) {
    int i = blockIdx.x * blockDim.x + threadIdx.x;
    if (i >= L) return;
    const float* row = XA + (size_t)sidx[i] * 16;
    float s = 0.f;
    #pragma unroll
    for (int f = 0; f < 16; ++f) s += row[f] * accum[f];
    pred[i] = s;
}

// ---------------------------------------------------------------------------
extern "C" void kernel_launch(void* const* d_in, const int* in_sizes, int n_in,
                              void* d_out, int out_size, void* d_ws, size_t ws_size,
                              hipStream_t stream) {
    const float* xA = (const float*)d_in[0];
    const float* xB = (const float*)d_in[1];
    const int* ei_ab = (const int*)d_in[2];
    const int* ei_ba = (const int*)d_in[3];
    const int* src_idx = (const int*)d_in[4];
    const int* dst_idx = (const int*)d_in[5];

    const int NAn = in_sizes[0] / 128;   // 50000
    const int NBn = in_sizes[1] / 128;   // 50000
    const int E   = in_sizes[2] / 2;     // 1e6
    const int L   = in_sizes[4];         // 1e5

    const float* Wab[3]  = {(const float*)d_in[6],  (const float*)d_in[14], (const float*)d_in[22]};
    const float* asab[3] = {(const float*)d_in[7],  (const float*)d_in[15], (const float*)d_in[23]};
    const float* adab[3] = {(const float*)d_in[8],  (const float*)d_in[16], (const float*)d_in[24]};
    const float* bab[3]  = {(const float*)d_in[9],  (const float*)d_in[17], (const float*)d_in[25]};
    const float* Wba[3]  = {(const float*)d_in[10], (const float*)d_in[18], (const float*)d_in[26]};
    const float* asba[3] = {(const float*)d_in[11], (const float*)d_in[19], (const float*)d_in[27]};
    const float* adba[3] = {(const float*)d_in[12], (const float*)d_in[20], (const float*)d_in[28]};
    const float* bba[3]  = {(const float*)d_in[13], (const float*)d_in[21], (const float*)d_in[29]};

    float* outp   = (float*)d_out;
    float* pred   = outp;
    float* xa_out = outp + L;
    float* xb_out = outp + L + (size_t)NAn * 16;

    // ---- workspace carve (~138 MB total) ----
    char* p = (char*)d_ws;
    auto alloc = [&](size_t n) { char* r = p; p += (n + 255) & ~(size_t)255; return r; };
    unsigned short* FA0 = (unsigned short*)alloc((size_t)NAn * 256 * 2);  // 25.6 MB
    unsigned short* FB0 = (unsigned short*)alloc((size_t)NBn * 256 * 2);
    unsigned short* FA1 = (unsigned short*)alloc((size_t)NAn * 256 * 2);
    unsigned short* FB1 = (unsigned short*)alloc((size_t)NBn * 256 * 2);
    unsigned short* Hb16 = (unsigned short*)alloc((size_t)NAn * 256 * 2); // also reused as fp32 [N][16]
    unsigned short* WT  = (unsigned short*)alloc((size_t)256 * 256 * 2);
    float* ssrc = (float*)alloc((size_t)NAn * 4);
    float* sdst = (float*)alloc((size_t)NAn * 4);
    float* wv   = (float*)alloc(256 * 4);
    int* csr_ab = (int*)alloc((size_t)E * 4);
    int* csr_ba = (int*)alloc((size_t)E * 4);
    int* off_ab = (int*)alloc((size_t)(NBn + 1) * 4);
    int* off_ba = (int*)alloc((size_t)(NAn + 1) * 4);
    int* cnt_ab = (int*)alloc((size_t)NBn * 4);
    int* cur_ab = (int*)alloc((size_t)NBn * 4);
    int* cnt_ba = (int*)alloc((size_t)NAn * 4);
    int* cur_ba = (int*)alloc((size_t)NAn * 4);
    float* accum16 = (float*)alloc(16 * 4);
    // guard: if workspace is smaller than our carve, bail cleanly (absmax will
    // show untouched output = diagnostic, instead of a GPU memory fault).
    if ((size_t)(p - (char*)d_ws) > ws_size) return;

    // ---- CSR build (edges identical across layers: build once per call) ----
    hipMemsetAsync(cnt_ab, 0, (size_t)NBn * 4, stream);
    hipMemsetAsync(cur_ab, 0, (size_t)NBn * 4, stream);
    hipMemsetAsync(cnt_ba, 0, (size_t)NAn * 4, stream);
    hipMemsetAsync(cur_ba, 0, (size_t)NAn * 4, stream);
    int eb = (E + 255) / 256;
    hist_kernel<<<eb, 256, 0, stream>>>(ei_ab + E, E, cnt_ab);
    exscan_kernel<<<1, 1024, 0, stream>>>(cnt_ab, off_ab, NBn);
    fill_kernel<<<eb, 256, 0, stream>>>(ei_ab, ei_ab + E, E, off_ab, cur_ab, csr_ab);
    hist_kernel<<<eb, 256, 0, stream>>>(ei_ba + E, E, cnt_ba);
    exscan_kernel<<<1, 1024, 0, stream>>>(cnt_ba, off_ba, NAn);
    fill_kernel<<<eb, 256, 0, stream>>>(ei_ba, ei_ba + E, E, off_ba, cur_ba, csr_ba);

    // ---- convert inputs to bf16 (layer-0 features, 128-wide) ----
    cvt_bf16_kernel<<<(NAn * 128 / 4 + 255) / 256, 256, 0, stream>>>(xA, FA0, NAn * 128 / 4);
    cvt_bf16_kernel<<<(NBn * 128 / 4 + 255) / 256, 256, 0, stream>>>(xB, FB0, NBn * 128 / 4);

    // ---- conv with Fout=256 (layers 0,1) ----
    auto conv256 = [&](const unsigned short* xs, const unsigned short* xd,
                       int Ns, int Nd, int Fin,
                       const float* W, const float* a_s, const float* a_d,
                       const float* bias, const int* off, const int* csr,
                       unsigned short* out, bool relu) {
        wt_bf16_kernel<<<(Fin * 256 + 255) / 256, 256, 0, stream>>>(W, WT, Fin, 256);
        dim3 gg((Ns + GBM - 1) / GBM, 256 / GBN);
        gemm_bf16<<<gg, 256, 0, stream>>>(xs, WT, Hb16, Ns, 256, Fin);
        rowdot_bf16<<<(Ns * 64 + 255) / 256, 256, 0, stream>>>(Hb16, a_s, ssrc, Ns, 256);
        rowdot_kernel<<<(Fin * 64 + 255) / 256, 256, 0, stream>>>(W, a_d, wv, Fin, 256);
        rowdot_bf16<<<(Nd * 64 + 255) / 256, 256, 0, stream>>>(xd, wv, sdst, Nd, Fin);
        int ab = (Nd + 3) / 4;
        if (relu)
            gat_agg256<true><<<ab, 256, 0, stream>>>(Hb16, ssrc, sdst, off, csr, bias, out, Nd);
        else
            gat_agg256<false><<<ab, 256, 0, stream>>>(Hb16, ssrc, sdst, off, csr, bias, out, Nd);
    };

    // ---- conv with Fout=16 (layer 2; Fin=256, fp32 H and output) ----
    auto conv16 = [&](const unsigned short* xs, const unsigned short* xd,
                      int Ns, int Nd,
                      const float* W, const float* a_s, const float* a_d,
                      const float* bias, const int* off, const int* csr,
                      float* out) {
        float* Hb32 = (float*)Hb16;
        gemm_bf16_n16<<<(Ns + 3) / 4, 256, 0, stream>>>(xs, W, Hb32, Ns);
        rowdot_kernel<<<(Ns * 64 + 255) / 256, 256, 0, stream>>>(Hb32, a_s, ssrc, Ns, 16);
        rowdot_kernel<<<(256 * 64 + 255) / 256, 256, 0, stream>>>(W, a_d, wv, 256, 16);
        rowdot_bf16<<<(Nd * 64 + 255) / 256, 256, 0, stream>>>(xd, wv, sdst, Nd, 256);
        gat_agg16<<<(Nd + 3) / 4, 256, 0, stream>>>(Hb32, ssrc, sdst, off, csr, bias, out, Nd);
    };

    // ---- 3 layers (ping-pong: FA0/FB0 <-> FA1/FB1) ----
    // layer 0: read FA0/FB0 (128-wide), write FA1/FB1 (256-wide)
    conv256(FA0, FB0, NAn, NBn, 128, Wab[0], asab[0], adab[0], bab[0], off_ab, csr_ab, FB1, true);
    conv256(FB0, FA0, NBn, NAn, 128, Wba[0], asba[0], adba[0], bba[0], off_ba, csr_ba, FA1, true);
    // layer 1: read FA1/FB1, write FA0/FB0 (256-wide)
    conv256(FA1, FB1, NAn, NBn, 256, Wab[1], asab[1], adab[1], bab[1], off_ab, csr_ab, FB0, true);
    conv256(FB1, FA1, NBn, NAn, 256, Wba[1], asba[1], adba[1], bba[1], off_ba, csr_ba, FA0, true);
    // layer 2: read FA0/FB0, write fp32 outputs
    conv16(FA0, FB0, NAn, NBn, Wab[2], asab[2], adab[2], bab[2], off_ab, csr_ab, xb_out);
    conv16(FB0, FA0, NBn, NAn, Wba[2], asba[2], adba[2], bba[2], off_ba, csr_ba, xa_out);

    // ---- epilogue ----
    hipMemsetAsync(accum16, 0, 16 * 4, stream);
    sum_rows16<<<128, 256, 0, stream>>>(xb_out, dst_idx, L, accum16);
    pred16<<<(L + 255) / 256, 256, 0, stream>>>(xa_out, src_idx, accum16, pred, L);
}

// Round 8
// 1217.799 us; speedup vs baseline: 1.2590x; 1.2590x over previous
//
#include <hip/hip_runtime.h>
#include <hip/hip_bf16.h>

#define WAVE 64

typedef __attribute__((ext_vector_type(8))) short short8;
typedef __attribute__((ext_vector_type(4))) float f32x4;

__device__ __forceinline__ unsigned short f32_to_bf16_rne(float f) {
    unsigned int u = __float_as_uint(f);
    u = u + 0x7fffu + ((u >> 16) & 1u);   // round-to-nearest-even
    return (unsigned short)(u >> 16);
}
__device__ __forceinline__ float bf16_to_f32(unsigned short h) {
    return __uint_as_float((unsigned int)h << 16);
}

// ---------------------------------------------------------------------------
// CSR build: histogram -> exclusive scan (single block) -> scatter fill
// ---------------------------------------------------------------------------
__global__ void hist_kernel(const int* __restrict__ dst, int E, int* __restrict__ cnt) {
    int e = blockIdx.x * blockDim.x + threadIdx.x;
    if (e < E) atomicAdd(&cnt[dst[e]], 1);
}

__global__ __launch_bounds__(1024) void exscan_kernel(const int* __restrict__ cnt,
                                                      int* __restrict__ off, int N) {
    __shared__ int part[1024];
    int t = threadIdx.x;
    int chunk = (N + 1023) / 1024;
    int lo = t * chunk;
    int hi = lo + chunk; if (hi > N) hi = N;
    int s = 0;
    for (int i = lo; i < hi; ++i) s += cnt[i];
    part[t] = s;
    __syncthreads();
    for (int o = 1; o < 1024; o <<= 1) {
        int v = (t >= o) ? part[t - o] : 0;
        __syncthreads();
        part[t] += v;
        __syncthreads();
    }
    int run = (t == 0) ? 0 : part[t - 1];
    for (int i = lo; i < hi; ++i) { off[i] = run; run += cnt[i]; }
    if (t == 1023) off[N] = part[1023];
}

__global__ void fill_kernel(const int* __restrict__ src, const int* __restrict__ dst, int E,
                            const int* __restrict__ off, int* __restrict__ cursor,
                            int* __restrict__ csr_src) {
    int e = blockIdx.x * blockDim.x + threadIdx.x;
    if (e < E) {
        int d = dst[e];
        int pos = off[d] + atomicAdd(&cursor[d], 1);
        csr_src[pos] = src[e];
    }
}

// ---------------------------------------------------------------------------
// fp32 -> bf16 convert (4 elems/thread)
// ---------------------------------------------------------------------------
__global__ void cvt_bf16_kernel(const float* __restrict__ in, unsigned short* __restrict__ out,
                                int n4) {
    int i = blockIdx.x * blockDim.x + threadIdx.x;
    if (i >= n4) return;
    float4 v = *(const float4*)(in + (size_t)i * 4);
    ushort4 o;
    o.x = f32_to_bf16_rne(v.x);
    o.y = f32_to_bf16_rne(v.y);
    o.z = f32_to_bf16_rne(v.z);
    o.w = f32_to_bf16_rne(v.w);
    *(ushort4*)(out + (size_t)i * 4) = o;
}

// W [K][N] fp32 -> WT [N][K] bf16
__global__ void wt_bf16_kernel(const float* __restrict__ W, unsigned short* __restrict__ WT,
                               int K, int N) {
    int idx = blockIdx.x * blockDim.x + threadIdx.x;
    if (idx >= K * N) return;
    int k = idx / N, n = idx - k * N;
    WT[(size_t)n * K + k] = f32_to_bf16_rne(W[idx]);
}

// ---------------------------------------------------------------------------
// rowdot fp32: out[n] = dot(X[n, 0:F], v[0:F])   (one wave per row)
// ---------------------------------------------------------------------------
__global__ void rowdot_kernel(const float* __restrict__ X, const float* __restrict__ v,
                              float* __restrict__ out, int N, int F) {
    int w = (blockIdx.x * blockDim.x + threadIdx.x) >> 6;
    int lane = threadIdx.x & 63;
    if (w >= N) return;
    const float* row = X + (size_t)w * F;
    float s = 0.f;
    for (int f = lane; f < F; f += WAVE) s += row[f] * v[f];
    #pragma unroll
    for (int o = 32; o; o >>= 1) s += __shfl_xor(s, o);
    if (lane == 0) out[w] = s;
}

// rowdot bf16 X (vectorized ushort4), fp32 v.  F multiple of 4.
__global__ void rowdot_bf16(const unsigned short* __restrict__ X, const float* __restrict__ v,
                            float* __restrict__ out, int N, int F) {
    int w = (blockIdx.x * blockDim.x + threadIdx.x) >> 6;
    int lane = threadIdx.x & 63;
    if (w >= N) return;
    const unsigned short* row = X + (size_t)w * F;
    float s = 0.f;
    for (int f = lane << 2; f < F; f += 256) {
        ushort4 hv = *(const ushort4*)(row + f);
        s += bf16_to_f32(hv.x) * v[f + 0] + bf16_to_f32(hv.y) * v[f + 1]
           + bf16_to_f32(hv.z) * v[f + 2] + bf16_to_f32(hv.w) * v[f + 3];
    }
    #pragma unroll
    for (int o = 32; o; o >>= 1) s += __shfl_xor(s, o);
    if (lane == 0) out[w] = s;
}

// ---------------------------------------------------------------------------
// bf16 MFMA GEMM: C[M,N] = A[M,K] @ BT[N,K]^T.  A,BT bf16; C bf16.
// Tile 128x64, 4 waves (2x2), BK=64, mfma_f32_16x16x32_bf16.
// Requires K % 64 == 0, N % 64 == 0.
// ---------------------------------------------------------------------------
#define GBM 128
#define GBN 64
#define GBK 64
#define LDP (GBK + 8)   // +8 bf16 pad: row stride 144B (9x16B) -> <=2-way conflict

__global__ __launch_bounds__(256) void gemm_bf16(const unsigned short* __restrict__ A,
                                                 const unsigned short* __restrict__ BT,
                                                 unsigned short* __restrict__ C,
                                                 int M, int N, int K) {
    __shared__ unsigned short As[GBM][LDP];
    __shared__ unsigned short Bs[GBN][LDP];

    int tid  = threadIdx.x;
    int lane = tid & 63;
    int wid  = tid >> 6;
    int wr   = wid >> 1;
    int wc   = wid & 1;
    int ln   = lane & 15;
    int hi   = lane >> 4;

    int row0 = blockIdx.x * GBM;
    int col0 = blockIdx.y * GBN;

    int sr = tid >> 3;
    int sk = (tid & 7) << 3;

    f32x4 acc[4][2];
    #pragma unroll
    for (int i = 0; i < 4; ++i)
        #pragma unroll
        for (int j = 0; j < 2; ++j)
            acc[i][j] = (f32x4){0.f, 0.f, 0.f, 0.f};

    for (int k0 = 0; k0 < K; k0 += GBK) {
        #pragma unroll
        for (int p = 0; p < 4; ++p) {
            int r = sr + p * 32;
            int gr = row0 + r;
            short8 v = (short8){0,0,0,0,0,0,0,0};
            if (gr < M)
                v = *(const short8*)(A + (size_t)gr * K + k0 + sk);
            *(short8*)&As[r][sk] = v;
        }
        #pragma unroll
        for (int p = 0; p < 2; ++p) {
            int r = sr + p * 32;
            short8 v = *(const short8*)(BT + (size_t)(col0 + r) * K + k0 + sk);
            *(short8*)&Bs[r][sk] = v;
        }
        __syncthreads();

        #pragma unroll
        for (int kk = 0; kk < 2; ++kk) {
            short8 a[4], b[2];
            #pragma unroll
            for (int mi = 0; mi < 4; ++mi)
                a[mi] = *(const short8*)&As[wr * 64 + mi * 16 + ln][kk * 32 + hi * 8];
            #pragma unroll
            for (int ni = 0; ni < 2; ++ni)
                b[ni] = *(const short8*)&Bs[wc * 32 + ni * 16 + ln][kk * 32 + hi * 8];
            #pragma unroll
            for (int mi = 0; mi < 4; ++mi)
                #pragma unroll
                for (int ni = 0; ni < 2; ++ni)
                    acc[mi][ni] = __builtin_amdgcn_mfma_f32_16x16x32_bf16(
                        a[mi], b[ni], acc[mi][ni], 0, 0, 0);
        }
        __syncthreads();
    }

    // C/D layout (verified m89/m91): col = lane&15, row = (lane>>4)*4 + reg
    #pragma unroll
    for (int mi = 0; mi < 4; ++mi) {
        #pragma unroll
        for (int ni = 0; ni < 2; ++ni) {
            int gcol = col0 + wc * 32 + ni * 16 + ln;
            #pragma unroll
            for (int r = 0; r < 4; ++r) {
                int grow = row0 + wr * 64 + mi * 16 + hi * 4 + r;
                if (grow < M) C[(size_t)grow * N + gcol] = f32_to_bf16_rne(acc[mi][ni][r]);
            }
        }
    }
}

// ---------------------------------------------------------------------------
// Final-layer GEMM: C[M,16] = A[M,256](bf16) @ B[256,16](fp32).  One wave/row.
// B staged in LDS (16 KB, shared by 4 waves); A read as ushort4.
// ---------------------------------------------------------------------------
__global__ __launch_bounds__(256) void gemm_bf16_n16(const unsigned short* __restrict__ A,
                                                     const float* __restrict__ B,
                                                     float* __restrict__ C, int M) {
    __shared__ float Bs[4096];
    for (int t = threadIdx.x; t < 4096; t += 256) Bs[t] = B[t];
    __syncthreads();
    int w = (blockIdx.x * blockDim.x + threadIdx.x) >> 6;
    int lane = threadIdx.x & 63;
    if (w >= M) return;
    int n = lane & 15, kg = lane >> 4;
    const unsigned short* row = A + (size_t)w * 256 + kg * 64;
    const float* Bp = Bs + kg * 64 * 16 + n;
    float s = 0.f;
    #pragma unroll
    for (int j = 0; j < 64; j += 4) {
        ushort4 a4 = *(const ushort4*)(row + j);
        s += bf16_to_f32(a4.x) * Bp[(j + 0) * 16]
           + bf16_to_f32(a4.y) * Bp[(j + 1) * 16]
           + bf16_to_f32(a4.z) * Bp[(j + 2) * 16]
           + bf16_to_f32(a4.w) * Bp[(j + 3) * 16];
    }
    s += __shfl_xor(s, 16);
    s += __shfl_xor(s, 32);
    if (lane < 16) C[(size_t)w * 16 + n] = s;
}

// ---------------------------------------------------------------------------
// GAT softmax + aggregation, Fout=256, bf16 H in / bf16 out. One wave per dst.
// Two-phase: (1) lane-parallel segment max; (2) per 64-edge chunk each lane
// computes its own exp-weight, then the gather loop broadcasts (w, src) from
// registers via shfl -- the H row load is the only memory op in the loop.
// den accumulates alongside (normalization commutes to the end).
// ---------------------------------------------------------------------------
template <bool RELU>
__global__ __launch_bounds__(256) void gat_agg256(
        const unsigned short* __restrict__ H, const float* __restrict__ ssrc,
        const float* __restrict__ sdst, const int* __restrict__ off,
        const int* __restrict__ csr, const float* __restrict__ bias,
        unsigned short* __restrict__ out, int Nd) {
    int wid = (blockIdx.x * blockDim.x + threadIdx.x) >> 6;
    int lane = threadIdx.x & 63;
    if (wid >= Nd) return;
    int s0 = off[wid], s1 = off[wid + 1];
    float sd = sdst[wid];

    // phase 1: segment max (lane-parallel)
    float mx = -1e30f;
    for (int i = s0 + lane; i < s1; i += WAVE) {
        float l = ssrc[csr[i]] + sd;
        l = (l > 0.f) ? l : 0.2f * l;
        mx = fmaxf(mx, l);
    }
    #pragma unroll
    for (int o = 32; o; o >>= 1) mx = fmaxf(mx, __shfl_xor(mx, o));
    float m = (s1 > s0) ? mx : 0.f;

    // phase 2: chunked weight computation + register-broadcast gather
    float den = 0.f;
    float4 acc = make_float4(0.f, 0.f, 0.f, 0.f);
    const int fo = lane << 2;
    for (int chunk = s0; chunk < s1; chunk += WAVE) {
        int i = chunk + lane;
        int si = 0; float w = 0.f;
        if (i < s1) {
            si = csr[i];
            float l = ssrc[si] + sd;
            l = (l > 0.f) ? l : 0.2f * l;
            w = __expf(l - m);
        }
        den += w;
        int cnt = min(WAVE, s1 - chunk);
        #pragma unroll 4
        for (int j = 0; j < cnt; ++j) {
            float wj = __shfl(w, j);
            int sj = __shfl(si, j);
            ushort4 hv = *(const ushort4*)(H + (size_t)sj * 256 + fo);
            acc.x += wj * bf16_to_f32(hv.x);
            acc.y += wj * bf16_to_f32(hv.y);
            acc.z += wj * bf16_to_f32(hv.z);
            acc.w += wj * bf16_to_f32(hv.w);
        }
    }
    #pragma unroll
    for (int o = 32; o; o >>= 1) den += __shfl_xor(den, o);
    float inv = 1.f / (den + 1e-16f);

    float4 bv = *(const float4*)(bias + fo);
    float4 o4;
    o4.x = acc.x * inv + bv.x;
    o4.y = acc.y * inv + bv.y;
    o4.z = acc.z * inv + bv.z;
    o4.w = acc.w * inv + bv.w;
    if (RELU) {
        o4.x = fmaxf(o4.x, 0.f); o4.y = fmaxf(o4.y, 0.f);
        o4.z = fmaxf(o4.z, 0.f); o4.w = fmaxf(o4.w, 0.f);
    }
    ushort4 ov;
    ov.x = f32_to_bf16_rne(o4.x);
    ov.y = f32_to_bf16_rne(o4.y);
    ov.z = f32_to_bf16_rne(o4.z);
    ov.w = f32_to_bf16_rne(o4.w);
    *(ushort4*)(out + (size_t)wid * 256 + fo) = ov;
}

// Fout=16, fp32 H / fp32 out (final layer, no relu). One wave per dst.
// 4 edges processed concurrently by 16-lane groups (lane = eg*16 + n).
__global__ __launch_bounds__(256) void gat_agg16(
        const float* __restrict__ H, const float* __restrict__ ssrc,
        const float* __restrict__ sdst, const int* __restrict__ off,
        const int* __restrict__ csr, const float* __restrict__ bias,
        float* __restrict__ out, int Nd) {
    int wid = (blockIdx.x * blockDim.x + threadIdx.x) >> 6;
    int lane = threadIdx.x & 63;
    if (wid >= Nd) return;
    int s0 = off[wid], s1 = off[wid + 1];
    float sd = sdst[wid];

    float mx = -1e30f;
    for (int i = s0 + lane; i < s1; i += WAVE) {
        float l = ssrc[csr[i]] + sd;
        l = (l > 0.f) ? l : 0.2f * l;
        mx = fmaxf(mx, l);
    }
    #pragma unroll
    for (int o = 32; o; o >>= 1) mx = fmaxf(mx, __shfl_xor(mx, o));
    float m = (s1 > s0) ? mx : 0.f;

    float den = 0.f;
    float acc = 0.f;
    int eg = lane >> 4, n = lane & 15;
    for (int chunk = s0; chunk < s1; chunk += WAVE) {
        int i = chunk + lane;
        int si = 0; float w = 0.f;
        if (i < s1) {
            si = csr[i];
            float l = ssrc[si] + sd;
            l = (l > 0.f) ? l : 0.2f * l;
            w = __expf(l - m);
        }
        den += w;
        int cnt = min(WAVE, s1 - chunk);
        for (int j0 = 0; j0 < cnt; j0 += 4) {
            int jj = j0 + eg;
            float wj = __shfl(w, jj & 63);
            int sj = __shfl(si, jj & 63);
            if (jj < cnt) acc += wj * H[(size_t)sj * 16 + n];
        }
    }
    #pragma unroll
    for (int o = 32; o; o >>= 1) den += __shfl_xor(den, o);
    float inv = 1.f / (den + 1e-16f);
    // reduce partial acc across the 4 edge-groups (lanes with same n)
    acc += __shfl_xor(acc, 16);
    acc += __shfl_xor(acc, 32);
    if (lane < 16)
        out[(size_t)wid * 16 + n] = acc * inv + bias[n];
}

// ---------------------------------------------------------------------------
// Epilogue
// ---------------------------------------------------------------------------
__global__ void sum_rows16(const float* __restrict__ X, const int* __restrict__ idx,
                           int L, float* __restrict__ accum) {
    __shared__ float red[16][16];
    int f = threadIdx.x & 15, r = threadIdx.x >> 4;
    float acc = 0.f;
    for (int i = blockIdx.x * 16 + r; i < L; i += gridDim.x * 16)
        acc += X[(size_t)idx[i] * 16 + f];
    red[r][f] = acc;
    __syncthreads();
    #pragma unroll
    for (int o = 8; o; o >>= 1) {
        if (r < o) red[r][f] += red[r + o][f];
        __syncthreads();
    }
    if (r == 0) atomicAdd(&accum[f], red[0][f]);
}

__global__ void pred16(const float* __restrict__ XA, const int* __restrict__ sidx,
                       const float* __restrict__ accum, float* __restrict__ pred, int L) {
    int i = blockIdx.x * blockDim.x + threadIdx.x;
    if (i >= L) return;
    const float* row = XA + (size_t)sidx[i] * 16;
    float s = 0.f;
    #pragma unroll
    for (int f = 0; f < 16; ++f) s += row[f] * accum[f];
    pred[i] = s;
}

// ---------------------------------------------------------------------------
extern "C" void kernel_launch(void* const* d_in, const int* in_sizes, int n_in,
                              void* d_out, int out_size, void* d_ws, size_t ws_size,
                              hipStream_t stream) {
    const float* xA = (const float*)d_in[0];
    const float* xB = (const float*)d_in[1];
    const int* ei_ab = (const int*)d_in[2];
    const int* ei_ba = (const int*)d_in[3];
    const int* src_idx = (const int*)d_in[4];
    const int* dst_idx = (const int*)d_in[5];

    const int NAn = in_sizes[0] / 128;   // 50000
    const int NBn = in_sizes[1] / 128;   // 50000
    const int E   = in_sizes[2] / 2;     // 1e6
    const int L   = in_sizes[4];         // 1e5

    const float* Wab[3]  = {(const float*)d_in[6],  (const float*)d_in[14], (const float*)d_in[22]};
    const float* asab[3] = {(const float*)d_in[7],  (const float*)d_in[15], (const float*)d_in[23]};
    const float* adab[3] = {(const float*)d_in[8],  (const float*)d_in[16], (const float*)d_in[24]};
    const float* bab[3]  = {(const float*)d_in[9],  (const float*)d_in[17], (const float*)d_in[25]};
    const float* Wba[3]  = {(const float*)d_in[10], (const float*)d_in[18], (const float*)d_in[26]};
    const float* asba[3] = {(const float*)d_in[11], (const float*)d_in[19], (const float*)d_in[27]};
    const float* adba[3] = {(const float*)d_in[12], (const float*)d_in[20], (const float*)d_in[28]};
    const float* bba[3]  = {(const float*)d_in[13], (const float*)d_in[21], (const float*)d_in[29]};

    float* outp   = (float*)d_out;
    float* pred   = outp;
    float* xa_out = outp + L;
    float* xb_out = outp + L + (size_t)NAn * 16;

    // ---- workspace carve (~138 MB total) ----
    char* p = (char*)d_ws;
    auto alloc = [&](size_t n) { char* r = p; p += (n + 255) & ~(size_t)255; return r; };
    unsigned short* FA0 = (unsigned short*)alloc((size_t)NAn * 256 * 2);
    unsigned short* FB0 = (unsigned short*)alloc((size_t)NBn * 256 * 2);
    unsigned short* FA1 = (unsigned short*)alloc((size_t)NAn * 256 * 2);
    unsigned short* FB1 = (unsigned short*)alloc((size_t)NBn * 256 * 2);
    unsigned short* Hb16 = (unsigned short*)alloc((size_t)NAn * 256 * 2); // reused as fp32 [N][16]
    unsigned short* WT  = (unsigned short*)alloc((size_t)256 * 256 * 2);
    float* ssrc = (float*)alloc((size_t)NAn * 4);
    float* sdst = (float*)alloc((size_t)NAn * 4);
    float* wv   = (float*)alloc(256 * 4);
    int* csr_ab = (int*)alloc((size_t)E * 4);
    int* csr_ba = (int*)alloc((size_t)E * 4);
    int* off_ab = (int*)alloc((size_t)(NBn + 1) * 4);
    int* off_ba = (int*)alloc((size_t)(NAn + 1) * 4);
    int* cnt_ab = (int*)alloc((size_t)NBn * 4);
    int* cur_ab = (int*)alloc((size_t)NBn * 4);
    int* cnt_ba = (int*)alloc((size_t)NAn * 4);
    int* cur_ba = (int*)alloc((size_t)NAn * 4);
    float* accum16 = (float*)alloc(16 * 4);
    if ((size_t)(p - (char*)d_ws) > ws_size) return;  // clean bail vs GPU fault

    // ---- CSR build (edges identical across layers: build once per call) ----
    hipMemsetAsync(cnt_ab, 0, (size_t)NBn * 4, stream);
    hipMemsetAsync(cur_ab, 0, (size_t)NBn * 4, stream);
    hipMemsetAsync(cnt_ba, 0, (size_t)NAn * 4, stream);
    hipMemsetAsync(cur_ba, 0, (size_t)NAn * 4, stream);
    int eb = (E + 255) / 256;
    hist_kernel<<<eb, 256, 0, stream>>>(ei_ab + E, E, cnt_ab);
    exscan_kernel<<<1, 1024, 0, stream>>>(cnt_ab, off_ab, NBn);
    fill_kernel<<<eb, 256, 0, stream>>>(ei_ab, ei_ab + E, E, off_ab, cur_ab, csr_ab);
    hist_kernel<<<eb, 256, 0, stream>>>(ei_ba + E, E, cnt_ba);
    exscan_kernel<<<1, 1024, 0, stream>>>(cnt_ba, off_ba, NAn);
    fill_kernel<<<eb, 256, 0, stream>>>(ei_ba, ei_ba + E, E, off_ba, cur_ba, csr_ba);

    // ---- convert inputs to bf16 (layer-0 features, 128-wide) ----
    cvt_bf16_kernel<<<(NAn * 128 / 4 + 255) / 256, 256, 0, stream>>>(xA, FA0, NAn * 128 / 4);
    cvt_bf16_kernel<<<(NBn * 128 / 4 + 255) / 256, 256, 0, stream>>>(xB, FB0, NBn * 128 / 4);

    // ---- conv with Fout=256 (layers 0,1) ----
    auto conv256 = [&](const unsigned short* xs, const unsigned short* xd,
                       int Ns, int Nd, int Fin,
                       const float* W, const float* a_s, const float* a_d,
                       const float* bias, const int* off, const int* csr,
                       unsigned short* out, bool relu) {
        wt_bf16_kernel<<<(Fin * 256 + 255) / 256, 256, 0, stream>>>(W, WT, Fin, 256);
        dim3 gg((Ns + GBM - 1) / GBM, 256 / GBN);
        gemm_bf16<<<gg, 256, 0, stream>>>(xs, WT, Hb16, Ns, 256, Fin);
        rowdot_bf16<<<(Ns * 64 + 255) / 256, 256, 0, stream>>>(Hb16, a_s, ssrc, Ns, 256);
        rowdot_kernel<<<(Fin * 64 + 255) / 256, 256, 0, stream>>>(W, a_d, wv, Fin, 256);
        rowdot_bf16<<<(Nd * 64 + 255) / 256, 256, 0, stream>>>(xd, wv, sdst, Nd, Fin);
        int ab = (Nd + 3) / 4;
        if (relu)
            gat_agg256<true><<<ab, 256, 0, stream>>>(Hb16, ssrc, sdst, off, csr, bias, out, Nd);
        else
            gat_agg256<false><<<ab, 256, 0, stream>>>(Hb16, ssrc, sdst, off, csr, bias, out, Nd);
    };

    // ---- conv with Fout=16 (layer 2; Fin=256, fp32 H and output) ----
    auto conv16 = [&](const unsigned short* xs, const unsigned short* xd,
                      int Ns, int Nd,
                      const float* W, const float* a_s, const float* a_d,
                      const float* bias, const int* off, const int* csr,
                      float* out) {
        float* Hb32 = (float*)Hb16;
        gemm_bf16_n16<<<(Ns + 3) / 4, 256, 0, stream>>>(xs, W, Hb32, Ns);
        rowdot_kernel<<<(Ns * 64 + 255) / 256, 256, 0, stream>>>(Hb32, a_s, ssrc, Ns, 16);
        rowdot_kernel<<<(256 * 64 + 255) / 256, 256, 0, stream>>>(W, a_d, wv, 256, 16);
        rowdot_bf16<<<(Nd * 64 + 255) / 256, 256, 0, stream>>>(xd, wv, sdst, Nd, 256);
        gat_agg16<<<(Nd + 3) / 4, 256, 0, stream>>>(Hb32, ssrc, sdst, off, csr, bias, out, Nd);
    };

    // ---- 3 layers (ping-pong: FA0/FB0 <-> FA1/FB1) ----
    conv256(FA0, FB0, NAn, NBn, 128, Wab[0], asab[0], adab[0], bab[0], off_ab, csr_ab, FB1, true);
    conv256(FB0, FA0, NBn, NAn, 128, Wba[0], asba[0], adba[0], bba[0], off_ba, csr_ba, FA1, true);
    conv256(FA1, FB1, NAn, NBn, 256, Wab[1], asab[1], adab[1], bab[1], off_ab, csr_ab, FB0, true);
    conv256(FB1, FA1, NBn, NAn, 256, Wba[1], asba[1], adba[1], bba[1], off_ba, csr_ba, FA0, true);
    conv16(FA0, FB0, NAn, NBn, Wab[2], asab[2], adab[2], bab[2], off_ab, csr_ab, xb_out);
    conv16(FB0, FA0, NBn, NAn, Wba[2], asba[2], adba[2], bba[2], off_ba, csr_ba, xa_out);

    // ---- epilogue ----
    hipMemsetAsync(accum16, 0, 16 * 4, stream);
    sum_rows16<<<128, 256, 0, stream>>>(xb_out, dst_idx, L, accum16);
    pred16<<<(L + 255) / 256, 256, 0, stream>>>(xa_out, src_idx, accum16, pred, L);
}

// Round 12
// 1177.302 us; speedup vs baseline: 1.3023x; 1.0344x over previous
//
#include <hip/hip_runtime.h>
#include <hip/hip_bf16.h>

#define WAVE 64

typedef __attribute__((ext_vector_type(8))) short short8;
typedef __attribute__((ext_vector_type(8))) unsigned short ushort8_t;
typedef __attribute__((ext_vector_type(4))) float f32x4;

__device__ __forceinline__ unsigned short f32_to_bf16_rne(float f) {
    unsigned int u = __float_as_uint(f);
    u = u + 0x7fffu + ((u >> 16) & 1u);   // round-to-nearest-even
    return (unsigned short)(u >> 16);
}
__device__ __forceinline__ float bf16_to_f32(unsigned short h) {
    return __uint_as_float((unsigned int)h << 16);
}

// ---------------------------------------------------------------------------
// CSR build: histogram -> exclusive scan (single block) -> scatter fill
// ---------------------------------------------------------------------------
__global__ void hist_kernel(const int* __restrict__ dst, int E, int* __restrict__ cnt) {
    int e = blockIdx.x * blockDim.x + threadIdx.x;
    if (e < E) atomicAdd(&cnt[dst[e]], 1);
}

__global__ __launch_bounds__(1024) void exscan_kernel(const int* __restrict__ cnt,
                                                      int* __restrict__ off, int N) {
    __shared__ int part[1024];
    int t = threadIdx.x;
    int chunk = (N + 1023) / 1024;
    int lo = t * chunk;
    int hi = lo + chunk; if (hi > N) hi = N;
    int s = 0;
    for (int i = lo; i < hi; ++i) s += cnt[i];
    part[t] = s;
    __syncthreads();
    for (int o = 1; o < 1024; o <<= 1) {
        int v = (t >= o) ? part[t - o] : 0;
        __syncthreads();
        part[t] += v;
        __syncthreads();
    }
    int run = (t == 0) ? 0 : part[t - 1];
    for (int i = lo; i < hi; ++i) { off[i] = run; run += cnt[i]; }
    if (t == 1023) off[N] = part[1023];
}

__global__ void fill_kernel(const int* __restrict__ src, const int* __restrict__ dst, int E,
                            const int* __restrict__ off, int* __restrict__ cursor,
                            int* __restrict__ csr_src) {
    int e = blockIdx.x * blockDim.x + threadIdx.x;
    if (e < E) {
        int d = dst[e];
        int pos = off[d] + atomicAdd(&cursor[d], 1);
        csr_src[pos] = src[e];
    }
}

// ---------------------------------------------------------------------------
// fp32 -> bf16 convert (4 elems/thread)
// ---------------------------------------------------------------------------
__global__ void cvt_bf16_kernel(const float* __restrict__ in, unsigned short* __restrict__ out,
                                int n4) {
    int i = blockIdx.x * blockDim.x + threadIdx.x;
    if (i >= n4) return;
    float4 v = *(const float4*)(in + (size_t)i * 4);
    ushort4 o;
    o.x = f32_to_bf16_rne(v.x);
    o.y = f32_to_bf16_rne(v.y);
    o.z = f32_to_bf16_rne(v.z);
    o.w = f32_to_bf16_rne(v.w);
    *(ushort4*)(out + (size_t)i * 4) = o;
}

// W [K][N] fp32 -> WT [N][K] bf16
__global__ void wt_bf16_kernel(const float* __restrict__ W, unsigned short* __restrict__ WT,
                               int K, int N) {
    int idx = blockIdx.x * blockDim.x + threadIdx.x;
    if (idx >= K * N) return;
    int k = idx / N, n = idx - k * N;
    WT[(size_t)n * K + k] = f32_to_bf16_rne(W[idx]);
}

// ---------------------------------------------------------------------------
// rowdot fp32: out[n] = dot(X[n, 0:F], v[0:F])   (one wave per row)
// ---------------------------------------------------------------------------
__global__ void rowdot_kernel(const float* __restrict__ X, const float* __restrict__ v,
                              float* __restrict__ out, int N, int F) {
    int w = (blockIdx.x * blockDim.x + threadIdx.x) >> 6;
    int lane = threadIdx.x & 63;
    if (w >= N) return;
    const float* row = X + (size_t)w * F;
    float s = 0.f;
    for (int f = lane; f < F; f += WAVE) s += row[f] * v[f];
    #pragma unroll
    for (int o = 32; o; o >>= 1) s += __shfl_xor(s, o);
    if (lane == 0) out[w] = s;
}

// rowdot bf16 X (vectorized ushort4), fp32 v.  F multiple of 4.
__global__ void rowdot_bf16(const unsigned short* __restrict__ X, const float* __restrict__ v,
                            float* __restrict__ out, int N, int F) {
    int w = (blockIdx.x * blockDim.x + threadIdx.x) >> 6;
    int lane = threadIdx.x & 63;
    if (w >= N) return;
    const unsigned short* row = X + (size_t)w * F;
    float s = 0.f;
    for (int f = lane << 2; f < F; f += 256) {
        ushort4 hv = *(const ushort4*)(row + f);
        s += bf16_to_f32(hv.x) * v[f + 0] + bf16_to_f32(hv.y) * v[f + 1]
           + bf16_to_f32(hv.z) * v[f + 2] + bf16_to_f32(hv.w) * v[f + 3];
    }
    #pragma unroll
    for (int o = 32; o; o >>= 1) s += __shfl_xor(s, o);
    if (lane == 0) out[w] = s;
}

// ---------------------------------------------------------------------------
// bf16 MFMA GEMM: C[M,N] = A[M,K] @ BT[N,K]^T.  A,BT bf16; C bf16.
// Tile 128x64, 4 waves (2x2), BK=64, mfma_f32_16x16x32_bf16.
// Requires K % 64 == 0, N % 64 == 0.   (round-8 verified version)
// ---------------------------------------------------------------------------
#define GBM 128
#define GBN 64
#define GBK 64
#define LDP (GBK + 8)   // +8 bf16 pad: row stride 144B (9x16B) -> <=2-way conflict

__global__ __launch_bounds__(256) void gemm_bf16(const unsigned short* __restrict__ A,
                                                 const unsigned short* __restrict__ BT,
                                                 unsigned short* __restrict__ C,
                                                 int M, int N, int K) {
    __shared__ unsigned short As[GBM][LDP];
    __shared__ unsigned short Bs[GBN][LDP];

    int tid  = threadIdx.x;
    int lane = tid & 63;
    int wid  = tid >> 6;
    int wr   = wid >> 1;
    int wc   = wid & 1;
    int ln   = lane & 15;
    int hi   = lane >> 4;

    int row0 = blockIdx.x * GBM;
    int col0 = blockIdx.y * GBN;

    int sr = tid >> 3;
    int sk = (tid & 7) << 3;

    f32x4 acc[4][2];
    #pragma unroll
    for (int i = 0; i < 4; ++i)
        #pragma unroll
        for (int j = 0; j < 2; ++j)
            acc[i][j] = (f32x4){0.f, 0.f, 0.f, 0.f};

    for (int k0 = 0; k0 < K; k0 += GBK) {
        #pragma unroll
        for (int p = 0; p < 4; ++p) {
            int r = sr + p * 32;
            int gr = row0 + r;
            short8 v = (short8){0,0,0,0,0,0,0,0};
            if (gr < M)
                v = *(const short8*)(A + (size_t)gr * K + k0 + sk);
            *(short8*)&As[r][sk] = v;
        }
        #pragma unroll
        for (int p = 0; p < 2; ++p) {
            int r = sr + p * 32;
            short8 v = *(const short8*)(BT + (size_t)(col0 + r) * K + k0 + sk);
            *(short8*)&Bs[r][sk] = v;
        }
        __syncthreads();

        #pragma unroll
        for (int kk = 0; kk < 2; ++kk) {
            short8 a[4], b[2];
            #pragma unroll
            for (int mi = 0; mi < 4; ++mi)
                a[mi] = *(const short8*)&As[wr * 64 + mi * 16 + ln][kk * 32 + hi * 8];
            #pragma unroll
            for (int ni = 0; ni < 2; ++ni)
                b[ni] = *(const short8*)&Bs[wc * 32 + ni * 16 + ln][kk * 32 + hi * 8];
            #pragma unroll
            for (int mi = 0; mi < 4; ++mi)
                #pragma unroll
                for (int ni = 0; ni < 2; ++ni)
                    acc[mi][ni] = __builtin_amdgcn_mfma_f32_16x16x32_bf16(
                        a[mi], b[ni], acc[mi][ni], 0, 0, 0);
        }
        __syncthreads();
    }

    // C/D layout (verified m89/m91): col = lane&15, row = (lane>>4)*4 + reg
    #pragma unroll
    for (int mi = 0; mi < 4; ++mi) {
        #pragma unroll
        for (int ni = 0; ni < 2; ++ni) {
            int gcol = col0 + wc * 32 + ni * 16 + ln;
            #pragma unroll
            for (int r = 0; r < 4; ++r) {
                int grow = row0 + wr * 64 + mi * 16 + hi * 4 + r;
                if (grow < M) C[(size_t)grow * N + gcol] = f32_to_bf16_rne(acc[mi][ni][r]);
            }
        }
    }
}

// ---------------------------------------------------------------------------
// Final-layer GEMM: C[M,16] = A[M,256](bf16) @ B[256,16](fp32).  One wave/row.
// B staged in LDS (16 KB, shared by 4 waves); A read as ushort4.
// ---------------------------------------------------------------------------
__global__ __launch_bounds__(256) void gemm_bf16_n16(const unsigned short* __restrict__ A,
                                                     const float* __restrict__ B,
                                                     float* __restrict__ C, int M) {
    __shared__ float Bs[4096];
    for (int t = threadIdx.x; t < 4096; t += 256) Bs[t] = B[t];
    __syncthreads();
    int w = (blockIdx.x * blockDim.x + threadIdx.x) >> 6;
    int lane = threadIdx.x & 63;
    if (w >= M) return;
    int n = lane & 15, kg = lane >> 4;
    const unsigned short* row = A + (size_t)w * 256 + kg * 64;
    const float* Bp = Bs + kg * 64 * 16 + n;
    float s = 0.f;
    #pragma unroll
    for (int j = 0; j < 64; j += 4) {
        ushort4 a4 = *(const ushort4*)(row + j);
        s += bf16_to_f32(a4.x) * Bp[(j + 0) * 16]
           + bf16_to_f32(a4.y) * Bp[(j + 1) * 16]
           + bf16_to_f32(a4.z) * Bp[(j + 2) * 16]
           + bf16_to_f32(a4.w) * Bp[(j + 3) * 16];
    }
    s += __shfl_xor(s, 16);
    s += __shfl_xor(s, 32);
    if (lane < 16) C[(size_t)w * 16 + n] = s;
}

// ---------------------------------------------------------------------------
// GAT softmax + aggregation, Fout=256, bf16 H in / bf16 out. One wave per dst.
// Paired-edge gather, FIXED: inner loop trip count is wave-UNIFORM
// (iters = ceil(cnt/2)); every __shfl executes with all 64 lanes active
// (AMD ds_bpermute from inactive lanes is undefined -- the round-9/10 bug).
// Only the load/accumulate is guarded by j < cnt.
// ---------------------------------------------------------------------------
template <bool RELU>
__global__ __launch_bounds__(256) void gat_agg256(
        const unsigned short* __restrict__ H, const float* __restrict__ ssrc,
        const float* __restrict__ sdst, const int* __restrict__ off,
        const int* __restrict__ csr, const float* __restrict__ bias,
        unsigned short* __restrict__ out, int Nd) {
    int wid = (blockIdx.x * blockDim.x + threadIdx.x) >> 6;
    int lane = threadIdx.x & 63;
    if (wid >= Nd) return;
    int s0 = off[wid], s1 = off[wid + 1];
    float sd = sdst[wid];

    // phase 1: segment max (lane-parallel)
    float mx = -1e30f;
    for (int i = s0 + lane; i < s1; i += WAVE) {
        float l = ssrc[csr[i]] + sd;
        l = (l > 0.f) ? l : 0.2f * l;
        mx = fmaxf(mx, l);
    }
    #pragma unroll
    for (int o = 32; o; o >>= 1) mx = fmaxf(mx, __shfl_xor(mx, o));
    float m = (s1 > s0) ? mx : 0.f;

    // phase 2: paired-edge register-broadcast gather (uniform trip count)
    int h = lane >> 5;            // which edge of the pair
    int fo = (lane & 31) << 3;    // 8-feature offset within the row
    float den = 0.f;
    float acc[8] = {0.f, 0.f, 0.f, 0.f, 0.f, 0.f, 0.f, 0.f};
    for (int chunk = s0; chunk < s1; chunk += WAVE) {
        int i = chunk + lane;
        int si = 0; float w = 0.f;
        if (i < s1) {
            si = csr[i];
            float l = ssrc[si] + sd;
            l = (l > 0.f) ? l : 0.2f * l;
            w = __expf(l - m);
        }
        den += w;
        int cnt = min(WAVE, s1 - chunk);     // uniform across the wave
        int iters = (cnt + 1) >> 1;          // uniform: both halves run iters
        for (int it = 0; it < iters; ++it) {
            int j = (it << 1) + h;           // half 0: even j, half 1: odd j
            int jc = (j < cnt) ? j : 0;      // clamp shfl source for safety
            float wj = __shfl(w, jc);        // all 64 lanes active here
            int sj = __shfl(si, jc);
            if (j < cnt) {
                ushort8_t hv = *(const ushort8_t*)(H + (size_t)sj * 256 + fo);
                #pragma unroll
                for (int t = 0; t < 8; ++t)
                    acc[t] += wj * bf16_to_f32(hv[t]);
            }
        }
    }
    #pragma unroll
    for (int o = 32; o; o >>= 1) den += __shfl_xor(den, o);
    float inv = 1.f / (den + 1e-16f);
    #pragma unroll
    for (int t = 0; t < 8; ++t) acc[t] += __shfl_xor(acc[t], 32);

    if (h == 0) {
        float bv[8];
        *(float4*)&bv[0] = *(const float4*)(bias + fo);
        *(float4*)&bv[4] = *(const float4*)(bias + fo + 4);
        ushort8_t ov;
        #pragma unroll
        for (int t = 0; t < 8; ++t) {
            float v = acc[t] * inv + bv[t];
            if (RELU) v = fmaxf(v, 0.f);
            ov[t] = f32_to_bf16_rne(v);
        }
        *(ushort8_t*)(out + (size_t)wid * 256 + fo) = ov;
    }
}

// Fout=16, fp32 H / fp32 out (final layer, no relu). One wave per dst.
// 4 edges processed concurrently by 16-lane groups (lane = eg*16 + n).
// (j0 loop bound is uniform; all shfls execute with full wave -- safe.)
__global__ __launch_bounds__(256) void gat_agg16(
        const float* __restrict__ H, const float* __restrict__ ssrc,
        const float* __restrict__ sdst, const int* __restrict__ off,
        const int* __restrict__ csr, const float* __restrict__ bias,
        float* __restrict__ out, int Nd) {
    int wid = (blockIdx.x * blockDim.x + threadIdx.x) >> 6;
    int lane = threadIdx.x & 63;
    if (wid >= Nd) return;
    int s0 = off[wid], s1 = off[wid + 1];
    float sd = sdst[wid];

    float mx = -1e30f;
    for (int i = s0 + lane; i < s1; i += WAVE) {
        float l = ssrc[csr[i]] + sd;
        l = (l > 0.f) ? l : 0.2f * l;
        mx = fmaxf(mx, l);
    }
    #pragma unroll
    for (int o = 32; o; o >>= 1) mx = fmaxf(mx, __shfl_xor(mx, o));
    float m = (s1 > s0) ? mx : 0.f;

    float den = 0.f;
    float acc = 0.f;
    int eg = lane >> 4, n = lane & 15;
    for (int chunk = s0; chunk < s1; chunk += WAVE) {
        int i = chunk + lane;
        int si = 0; float w = 0.f;
        if (i < s1) {
            si = csr[i];
            float l = ssrc[si] + sd;
            l = (l > 0.f) ? l : 0.2f * l;
            w = __expf(l - m);
        }
        den += w;
        int cnt = min(WAVE, s1 - chunk);
        for (int j0 = 0; j0 < cnt; j0 += 4) {
            int jj = j0 + eg;
            float wj = __shfl(w, jj & 63);
            int sj = __shfl(si, jj & 63);
            if (jj < cnt) acc += wj * H[(size_t)sj * 16 + n];
        }
    }
    #pragma unroll
    for (int o = 32; o; o >>= 1) den += __shfl_xor(den, o);
    float inv = 1.f / (den + 1e-16f);
    acc += __shfl_xor(acc, 16);
    acc += __shfl_xor(acc, 32);
    if (lane < 16)
        out[(size_t)wid * 16 + n] = acc * inv + bias[n];
}

// ---------------------------------------------------------------------------
// Epilogue
// ---------------------------------------------------------------------------
__global__ void sum_rows16(const float* __restrict__ X, const int* __restrict__ idx,
                           int L, float* __restrict__ accum) {
    __shared__ float red[16][16];
    int f = threadIdx.x & 15, r = threadIdx.x >> 4;
    float acc = 0.f;
    for (int i = blockIdx.x * 16 + r; i < L; i += gridDim.x * 16)
        acc += X[(size_t)idx[i] * 16 + f];
    red[r][f] = acc;
    __syncthreads();
    #pragma unroll
    for (int o = 8; o; o >>= 1) {
        if (r < o) red[r][f] += red[r + o][f];
        __syncthreads();
    }
    if (r == 0) atomicAdd(&accum[f], red[0][f]);
}

__global__ void pred16(const float* __restrict__ XA, const int* __restrict__ sidx,
                       const float* __restrict__ accum, float* __restrict__ pred, int L) {
    int i = blockIdx.x * blockDim.x + threadIdx.x;
    if (i >= L) return;
    const float* row = XA + (size_t)sidx[i] * 16;
    float s = 0.f;
    #pragma unroll
    for (int f = 0; f < 16; ++f) s += row[f] * accum[f];
    pred[i] = s;
}

// ---------------------------------------------------------------------------
extern "C" void kernel_launch(void* const* d_in, const int* in_sizes, int n_in,
                              void* d_out, int out_size, void* d_ws, size_t ws_size,
                              hipStream_t stream) {
    const float* xA = (const float*)d_in[0];
    const float* xB = (const float*)d_in[1];
    const int* ei_ab = (const int*)d_in[2];
    const int* ei_ba = (const int*)d_in[3];
    const int* src_idx = (const int*)d_in[4];
    const int* dst_idx = (const int*)d_in[5];

    const int NAn = in_sizes[0] / 128;   // 50000
    const int NBn = in_sizes[1] / 128;   // 50000
    const int E   = in_sizes[2] / 2;     // 1e6
    const int L   = in_sizes[4];         // 1e5

    const float* Wab[3]  = {(const float*)d_in[6],  (const float*)d_in[14], (const float*)d_in[22]};
    const float* asab[3] = {(const float*)d_in[7],  (const float*)d_in[15], (const float*)d_in[23]};
    const float* adab[3] = {(const float*)d_in[8],  (const float*)d_in[16], (const float*)d_in[24]};
    const float* bab[3]  = {(const float*)d_in[9],  (const float*)d_in[17], (const float*)d_in[25]};
    const float* Wba[3]  = {(const float*)d_in[10], (const float*)d_in[18], (const float*)d_in[26]};
    const float* asba[3] = {(const float*)d_in[11], (const float*)d_in[19], (const float*)d_in[27]};
    const float* adba[3] = {(const float*)d_in[12], (const float*)d_in[20], (const float*)d_in[28]};
    const float* bba[3]  = {(const float*)d_in[13], (const float*)d_in[21], (const float*)d_in[29]};

    float* outp   = (float*)d_out;
    float* pred   = outp;
    float* xa_out = outp + L;
    float* xb_out = outp + L + (size_t)NAn * 16;

    // ---- workspace carve (~138 MB total) ----
    char* p = (char*)d_ws;
    auto alloc = [&](size_t n) { char* r = p; p += (n + 255) & ~(size_t)255; return r; };
    unsigned short* FA0 = (unsigned short*)alloc((size_t)NAn * 256 * 2);
    unsigned short* FB0 = (unsigned short*)alloc((size_t)NBn * 256 * 2);
    unsigned short* FA1 = (unsigned short*)alloc((size_t)NAn * 256 * 2);
    unsigned short* FB1 = (unsigned short*)alloc((size_t)NBn * 256 * 2);
    unsigned short* Hb16 = (unsigned short*)alloc((size_t)NAn * 256 * 2); // reused as fp32 [N][16]
    unsigned short* WT  = (unsigned short*)alloc((size_t)256 * 256 * 2);
    float* ssrc = (float*)alloc((size_t)NAn * 4);
    float* sdst = (float*)alloc((size_t)NAn * 4);
    float* wv   = (float*)alloc(256 * 4);
    int* csr_ab = (int*)alloc((size_t)E * 4);
    int* csr_ba = (int*)alloc((size_t)E * 4);
    int* off_ab = (int*)alloc((size_t)(NBn + 1) * 4);
    int* off_ba = (int*)alloc((size_t)(NAn + 1) * 4);
    int* cnt_ab = (int*)alloc((size_t)NBn * 4);
    int* cur_ab = (int*)alloc((size_t)NBn * 4);
    int* cnt_ba = (int*)alloc((size_t)NAn * 4);
    int* cur_ba = (int*)alloc((size_t)NAn * 4);
    float* accum16 = (float*)alloc(16 * 4);
    if ((size_t)(p - (char*)d_ws) > ws_size) return;  // clean bail vs GPU fault

    // ---- CSR build (edges identical across layers: build once per call) ----
    hipMemsetAsync(cnt_ab, 0, (size_t)NBn * 4, stream);
    hipMemsetAsync(cur_ab, 0, (size_t)NBn * 4, stream);
    hipMemsetAsync(cnt_ba, 0, (size_t)NAn * 4, stream);
    hipMemsetAsync(cur_ba, 0, (size_t)NAn * 4, stream);
    int eb = (E + 255) / 256;
    hist_kernel<<<eb, 256, 0, stream>>>(ei_ab + E, E, cnt_ab);
    exscan_kernel<<<1, 1024, 0, stream>>>(cnt_ab, off_ab, NBn);
    fill_kernel<<<eb, 256, 0, stream>>>(ei_ab, ei_ab + E, E, off_ab, cur_ab, csr_ab);
    hist_kernel<<<eb, 256, 0, stream>>>(ei_ba + E, E, cnt_ba);
    exscan_kernel<<<1, 1024, 0, stream>>>(cnt_ba, off_ba, NAn);
    fill_kernel<<<eb, 256, 0, stream>>>(ei_ba, ei_ba + E, E, off_ba, cur_ba, csr_ba);

    // ---- convert inputs to bf16 (layer-0 features, 128-wide) ----
    cvt_bf16_kernel<<<(NAn * 128 / 4 + 255) / 256, 256, 0, stream>>>(xA, FA0, NAn * 128 / 4);
    cvt_bf16_kernel<<<(NBn * 128 / 4 + 255) / 256, 256, 0, stream>>>(xB, FB0, NBn * 128 / 4);

    // ---- conv with Fout=256 (layers 0,1) ----
    auto conv256 = [&](const unsigned short* xs, const unsigned short* xd,
                       int Ns, int Nd, int Fin,
                       const float* W, const float* a_s, const float* a_d,
                       const float* bias, const int* off, const int* csr,
                       unsigned short* out, bool relu) {
        wt_bf16_kernel<<<(Fin * 256 + 255) / 256, 256, 0, stream>>>(W, WT, Fin, 256);
        dim3 gg((Ns + GBM - 1) / GBM, 256 / GBN);
        gemm_bf16<<<gg, 256, 0, stream>>>(xs, WT, Hb16, Ns, 256, Fin);
        rowdot_bf16<<<(Ns * 64 + 255) / 256, 256, 0, stream>>>(Hb16, a_s, ssrc, Ns, 256);
        rowdot_kernel<<<(Fin * 64 + 255) / 256, 256, 0, stream>>>(W, a_d, wv, Fin, 256);
        rowdot_bf16<<<(Nd * 64 + 255) / 256, 256, 0, stream>>>(xd, wv, sdst, Nd, Fin);
        int ab = (Nd + 3) / 4;
        if (relu)
            gat_agg256<true><<<ab, 256, 0, stream>>>(Hb16, ssrc, sdst, off, csr, bias, out, Nd);
        else
            gat_agg256<false><<<ab, 256, 0, stream>>>(Hb16, ssrc, sdst, off, csr, bias, out, Nd);
    };

    // ---- conv with Fout=16 (layer 2; Fin=256, fp32 H and output) ----
    auto conv16 = [&](const unsigned short* xs, const unsigned short* xd,
                      int Ns, int Nd,
                      const float* W, const float* a_s, const float* a_d,
                      const float* bias, const int* off, const int* csr,
                      float* out) {
        float* Hb32 = (float*)Hb16;
        gemm_bf16_n16<<<(Ns + 3) / 4, 256, 0, stream>>>(xs, W, Hb32, Ns);
        rowdot_kernel<<<(Ns * 64 + 255) / 256, 256, 0, stream>>>(Hb32, a_s, ssrc, Ns, 16);
        rowdot_kernel<<<(256 * 64 + 255) / 256, 256, 0, stream>>>(W, a_d, wv, 256, 16);
        rowdot_bf16<<<(Nd * 64 + 255) / 256, 256, 0, stream>>>(xd, wv, sdst, Nd, 256);
        gat_agg16<<<(Nd + 3) / 4, 256, 0, stream>>>(Hb32, ssrc, sdst, off, csr, bias, out, Nd);
    };

    // ---- 3 layers (ping-pong: FA0/FB0 <-> FA1/FB1) ----
    conv256(FA0, FB0, NAn, NBn, 128, Wab[0], asab[0], adab[0], bab[0], off_ab, csr_ab, FB1, true);
    conv256(FB0, FA0, NBn, NAn, 128, Wba[0], asba[0], adba[0], bba[0], off_ba, csr_ba, FA1, true);
    conv256(FA1, FB1, NAn, NBn, 256, Wab[1], asab[1], adab[1], bab[1], off_ab, csr_ab, FB0, true);
    conv256(FB1, FA1, NBn, NAn, 256, Wba[1], asba[1], adba[1], bba[1], off_ba, csr_ba, FA0, true);
    conv16(FA0, FB0, NAn, NBn, Wab[2], asab[2], adab[2], bab[2], off_ab, csr_ab, xb_out);
    conv16(FB0, FA0, NBn, NAn, Wba[2], asba[2], adba[2], bba[2], off_ba, csr_ba, xa_out);

    // ---- epilogue ----
    hipMemsetAsync(accum16, 0, 16 * 4, stream);
    sum_rows16<<<128, 256, 0, stream>>>(xb_out, dst_idx, L, accum16);
    pred16<<<(L + 255) / 256, 256, 0, stream>>>(xa_out, src_idx, accum16, pred, L);
}

// Round 15
// 1041.702 us; speedup vs baseline: 1.4718x; 1.1302x over previous
//
#include <hip/hip_runtime.h>
#include <hip/hip_bf16.h>

#define WAVE 64

typedef __attribute__((ext_vector_type(8))) short short8;
typedef __attribute__((ext_vector_type(8))) unsigned short ushort8_t;
typedef __attribute__((ext_vector_type(4))) float f32x4;

__device__ __forceinline__ unsigned short f32_to_bf16_rne(float f) {
    unsigned int u = __float_as_uint(f);
    u = u + 0x7fffu + ((u >> 16) & 1u);   // round-to-nearest-even
    return (unsigned short)(u >> 16);
}
__device__ __forceinline__ float bf16_to_f32(unsigned short h) {
    return __uint_as_float((unsigned int)h << 16);
}

// ---------------------------------------------------------------------------
// CSR build: histogram -> hierarchical exclusive scan (3 kernels) -> fill
// ---------------------------------------------------------------------------
__global__ void hist_kernel(const int* __restrict__ dst, int E, int* __restrict__ cnt) {
    int e = blockIdx.x * blockDim.x + threadIdx.x;
    if (e < E) atomicAdd(&cnt[dst[e]], 1);
}

// 1) per-256-chunk sums (tree reduce in LDS)
__global__ __launch_bounds__(256) void chunk_sum_kernel(const int* __restrict__ cnt,
                                                        int* __restrict__ csum, int N) {
    __shared__ int red[256];
    int t = threadIdx.x;
    int i = blockIdx.x * 256 + t;
    red[t] = (i < N) ? cnt[i] : 0;
    __syncthreads();
    #pragma unroll
    for (int o = 128; o; o >>= 1) {
        if (t < o) red[t] += red[t + o];
        __syncthreads();
    }
    if (t == 0) csum[blockIdx.x] = red[0];
}

// 2) single-block exclusive scan of chunk sums (C <= 1024); writes grand total
__global__ __launch_bounds__(1024) void exscan_sums_kernel(const int* __restrict__ csum,
                                                           int* __restrict__ cbase, int C,
                                                           int* __restrict__ totalOut) {
    __shared__ int part[1024];
    int t = threadIdx.x;
    part[t] = (t < C) ? csum[t] : 0;
    __syncthreads();
    for (int o = 1; o < 1024; o <<= 1) {
        int v = (t >= o) ? part[t - o] : 0;
        __syncthreads();
        part[t] += v;
        __syncthreads();
    }
    if (t < C) cbase[t] = (t == 0) ? 0 : part[t - 1];
    if (t == 1023) *totalOut = part[1023];
}

// 3) per-chunk exclusive scan + chunk base -> off[i]
__global__ __launch_bounds__(256) void chunk_scan_kernel(const int* __restrict__ cnt,
                                                         const int* __restrict__ cbase,
                                                         int* __restrict__ off, int N) {
    __shared__ int s[256];
    int t = threadIdx.x;
    int i = blockIdx.x * 256 + t;
    s[t] = (i < N) ? cnt[i] : 0;
    __syncthreads();
    for (int o = 1; o < 256; o <<= 1) {
        int v = (t >= o) ? s[t - o] : 0;
        __syncthreads();
        s[t] += v;
        __syncthreads();
    }
    if (i < N) off[i] = cbase[blockIdx.x] + ((t == 0) ? 0 : s[t - 1]);
}

__global__ void fill_kernel(const int* __restrict__ src, const int* __restrict__ dst, int E,
                            const int* __restrict__ off, int* __restrict__ cursor,
                            int* __restrict__ csr_src) {
    int e = blockIdx.x * blockDim.x + threadIdx.x;
    if (e < E) {
        int d = dst[e];
        int pos = off[d] + atomicAdd(&cursor[d], 1);
        csr_src[pos] = src[e];
    }
}

// ---------------------------------------------------------------------------
// fp32 -> bf16 convert (4 elems/thread)
// ---------------------------------------------------------------------------
__global__ void cvt_bf16_kernel(const float* __restrict__ in, unsigned short* __restrict__ out,
                                int n4) {
    int i = blockIdx.x * blockDim.x + threadIdx.x;
    if (i >= n4) return;
    float4 v = *(const float4*)(in + (size_t)i * 4);
    ushort4 o;
    o.x = f32_to_bf16_rne(v.x);
    o.y = f32_to_bf16_rne(v.y);
    o.z = f32_to_bf16_rne(v.z);
    o.w = f32_to_bf16_rne(v.w);
    *(ushort4*)(out + (size_t)i * 4) = o;
}

// W [K][N] fp32 -> WT [N][K] bf16
__global__ void wt_bf16_kernel(const float* __restrict__ W, unsigned short* __restrict__ WT,
                               int K, int N) {
    int idx = blockIdx.x * blockDim.x + threadIdx.x;
    if (idx >= K * N) return;
    int k = idx / N, n = idx - k * N;
    WT[(size_t)n * K + k] = f32_to_bf16_rne(W[idx]);
}

// ---------------------------------------------------------------------------
// rowdot fp32: out[n] = dot(X[n, 0:F], v[0:F])   (one wave per row)
// ---------------------------------------------------------------------------
__global__ void rowdot_kernel(const float* __restrict__ X, const float* __restrict__ v,
                              float* __restrict__ out, int N, int F) {
    int w = (blockIdx.x * blockDim.x + threadIdx.x) >> 6;
    int lane = threadIdx.x & 63;
    if (w >= N) return;
    const float* row = X + (size_t)w * F;
    float s = 0.f;
    for (int f = lane; f < F; f += WAVE) s += row[f] * v[f];
    #pragma unroll
    for (int o = 32; o; o >>= 1) s += __shfl_xor(s, o);
    if (lane == 0) out[w] = s;
}

// rowdot bf16 X (vectorized ushort4), fp32 v.  F multiple of 4.
__global__ void rowdot_bf16(const unsigned short* __restrict__ X, const float* __restrict__ v,
                            float* __restrict__ out, int N, int F) {
    int w = (blockIdx.x * blockDim.x + threadIdx.x) >> 6;
    int lane = threadIdx.x & 63;
    if (w >= N) return;
    const unsigned short* row = X + (size_t)w * F;
    float s = 0.f;
    for (int f = lane << 2; f < F; f += 256) {
        ushort4 hv = *(const ushort4*)(row + f);
        s += bf16_to_f32(hv.x) * v[f + 0] + bf16_to_f32(hv.y) * v[f + 1]
           + bf16_to_f32(hv.z) * v[f + 2] + bf16_to_f32(hv.w) * v[f + 3];
    }
    #pragma unroll
    for (int o = 32; o; o >>= 1) s += __shfl_xor(s, o);
    if (lane == 0) out[w] = s;
}

// ---------------------------------------------------------------------------
// bf16 MFMA GEMM: C[M,N] = A[M,K] @ BT[N,K]^T.  A,BT bf16; C bf16.
// Tile 128x64, 4 waves (2x2), BK=64, mfma_f32_16x16x32_bf16.
// Requires K % 64 == 0, N % 64 == 0.   (round-8 verified version)
// ---------------------------------------------------------------------------
#define GBM 128
#define GBN 64
#define GBK 64
#define LDP (GBK + 8)   // +8 bf16 pad: row stride 144B (9x16B) -> <=2-way conflict

__global__ __launch_bounds__(256) void gemm_bf16(const unsigned short* __restrict__ A,
                                                 const unsigned short* __restrict__ BT,
                                                 unsigned short* __restrict__ C,
                                                 int M, int N, int K) {
    __shared__ unsigned short As[GBM][LDP];
    __shared__ unsigned short Bs[GBN][LDP];

    int tid  = threadIdx.x;
    int lane = tid & 63;
    int wid  = tid >> 6;
    int wr   = wid >> 1;
    int wc   = wid & 1;
    int ln   = lane & 15;
    int hi   = lane >> 4;

    int row0 = blockIdx.x * GBM;
    int col0 = blockIdx.y * GBN;

    int sr = tid >> 3;
    int sk = (tid & 7) << 3;

    f32x4 acc[4][2];
    #pragma unroll
    for (int i = 0; i < 4; ++i)
        #pragma unroll
        for (int j = 0; j < 2; ++j)
            acc[i][j] = (f32x4){0.f, 0.f, 0.f, 0.f};

    for (int k0 = 0; k0 < K; k0 += GBK) {
        #pragma unroll
        for (int p = 0; p < 4; ++p) {
            int r = sr + p * 32;
            int gr = row0 + r;
            short8 v = (short8){0,0,0,0,0,0,0,0};
            if (gr < M)
                v = *(const short8*)(A + (size_t)gr * K + k0 + sk);
            *(short8*)&As[r][sk] = v;
        }
        #pragma unroll
        for (int p = 0; p < 2; ++p) {
            int r = sr + p * 32;
            short8 v = *(const short8*)(BT + (size_t)(col0 + r) * K + k0 + sk);
            *(short8*)&Bs[r][sk] = v;
        }
        __syncthreads();

        #pragma unroll
        for (int kk = 0; kk < 2; ++kk) {
            short8 a[4], b[2];
            #pragma unroll
            for (int mi = 0; mi < 4; ++mi)
                a[mi] = *(const short8*)&As[wr * 64 + mi * 16 + ln][kk * 32 + hi * 8];
            #pragma unroll
            for (int ni = 0; ni < 2; ++ni)
                b[ni] = *(const short8*)&Bs[wc * 32 + ni * 16 + ln][kk * 32 + hi * 8];
            #pragma unroll
            for (int mi = 0; mi < 4; ++mi)
                #pragma unroll
                for (int ni = 0; ni < 2; ++ni)
                    acc[mi][ni] = __builtin_amdgcn_mfma_f32_16x16x32_bf16(
                        a[mi], b[ni], acc[mi][ni], 0, 0, 0);
        }
        __syncthreads();
    }

    // C/D layout (verified m89/m91): col = lane&15, row = (lane>>4)*4 + reg
    #pragma unroll
    for (int mi = 0; mi < 4; ++mi) {
        #pragma unroll
        for (int ni = 0; ni < 2; ++ni) {
            int gcol = col0 + wc * 32 + ni * 16 + ln;
            #pragma unroll
            for (int r = 0; r < 4; ++r) {
                int grow = row0 + wr * 64 + mi * 16 + hi * 4 + r;
                if (grow < M) C[(size_t)grow * N + gcol] = f32_to_bf16_rne(acc[mi][ni][r]);
            }
        }
    }
}

// ---------------------------------------------------------------------------
// Final-layer GEMM: C[M,16] = A[M,256](bf16) @ B[256,16](fp32).  One wave/row.
// B staged in LDS (16 KB, shared by 4 waves); A read as ushort4.
// ---------------------------------------------------------------------------
__global__ __launch_bounds__(256) void gemm_bf16_n16(const unsigned short* __restrict__ A,
                                                     const float* __restrict__ B,
                                                     float* __restrict__ C, int M) {
    __shared__ float Bs[4096];
    for (int t = threadIdx.x; t < 4096; t += 256) Bs[t] = B[t];
    __syncthreads();
    int w = (blockIdx.x * blockDim.x + threadIdx.x) >> 6;
    int lane = threadIdx.x & 63;
    if (w >= M) return;
    int n = lane & 15, kg = lane >> 4;
    const unsigned short* row = A + (size_t)w * 256 + kg * 64;
    const float* Bp = Bs + kg * 64 * 16 + n;
    float s = 0.f;
    #pragma unroll
    for (int j = 0; j < 64; j += 4) {
        ushort4 a4 = *(const ushort4*)(row + j);
        s += bf16_to_f32(a4.x) * Bp[(j + 0) * 16]
           + bf16_to_f32(a4.y) * Bp[(j + 1) * 16]
           + bf16_to_f32(a4.z) * Bp[(j + 2) * 16]
           + bf16_to_f32(a4.w) * Bp[(j + 3) * 16];
    }
    s += __shfl_xor(s, 16);
    s += __shfl_xor(s, 32);
    if (lane < 16) C[(size_t)w * 16 + n] = s;
}

// ---------------------------------------------------------------------------
// GAT softmax + aggregation, Fout=256, bf16 H in / bf16 out. One wave per dst.
// Paired-edge gather with wave-UNIFORM inner trip count (all shfls full-wave;
// AMD ds_bpermute from inactive lanes is undefined -- verified round-11 bug).
// ---------------------------------------------------------------------------
template <bool RELU>
__global__ __launch_bounds__(256) void gat_agg256(
        const unsigned short* __restrict__ H, const float* __restrict__ ssrc,
        const float* __restrict__ sdst, const int* __restrict__ off,
        const int* __restrict__ csr, const float* __restrict__ bias,
        unsigned short* __restrict__ out, int Nd) {
    int wid = (blockIdx.x * blockDim.x + threadIdx.x) >> 6;
    int lane = threadIdx.x & 63;
    if (wid >= Nd) return;
    int s0 = off[wid], s1 = off[wid + 1];
    float sd = sdst[wid];

    // phase 1: segment max (lane-parallel)
    float mx = -1e30f;
    for (int i = s0 + lane; i < s1; i += WAVE) {
        float l = ssrc[csr[i]] + sd;
        l = (l > 0.f) ? l : 0.2f * l;
        mx = fmaxf(mx, l);
    }
    #pragma unroll
    for (int o = 32; o; o >>= 1) mx = fmaxf(mx, __shfl_xor(mx, o));
    float m = (s1 > s0) ? mx : 0.f;

    // phase 2: paired-edge register-broadcast gather (uniform trip count)
    int h = lane >> 5;            // which edge of the pair
    int fo = (lane & 31) << 3;    // 8-feature offset within the row
    float den = 0.f;
    float acc[8] = {0.f, 0.f, 0.f, 0.f, 0.f, 0.f, 0.f, 0.f};
    for (int chunk = s0; chunk < s1; chunk += WAVE) {
        int i = chunk + lane;
        int si = 0; float w = 0.f;
        if (i < s1) {
            si = csr[i];
            float l = ssrc[si] + sd;
            l = (l > 0.f) ? l : 0.2f * l;
            w = __expf(l - m);
        }
        den += w;
        int cnt = min(WAVE, s1 - chunk);     // uniform across the wave
        int iters = (cnt + 1) >> 1;          // uniform: both halves run iters
        for (int it = 0; it < iters; ++it) {
            int j = (it << 1) + h;           // half 0: even j, half 1: odd j
            int jc = (j < cnt) ? j : 0;      // clamp shfl source
            float wj = __shfl(w, jc);        // all 64 lanes active here
            int sj = __shfl(si, jc);
            if (j < cnt) {
                ushort8_t hv = *(const ushort8_t*)(H + (size_t)sj * 256 + fo);
                #pragma unroll
                for (int t = 0; t < 8; ++t)
                    acc[t] += wj * bf16_to_f32(hv[t]);
            }
        }
    }
    #pragma unroll
    for (int o = 32; o; o >>= 1) den += __shfl_xor(den, o);
    float inv = 1.f / (den + 1e-16f);
    #pragma unroll
    for (int t = 0; t < 8; ++t) acc[t] += __shfl_xor(acc[t], 32);

    if (h == 0) {
        float bv[8];
        *(float4*)&bv[0] = *(const float4*)(bias + fo);
        *(float4*)&bv[4] = *(const float4*)(bias + fo + 4);
        ushort8_t ov;
        #pragma unroll
        for (int t = 0; t < 8; ++t) {
            float v = acc[t] * inv + bv[t];
            if (RELU) v = fmaxf(v, 0.f);
            ov[t] = f32_to_bf16_rne(v);
        }
        *(ushort8_t*)(out + (size_t)wid * 256 + fo) = ov;
    }
}

// Fout=16, fp32 H / fp32 out (final layer, no relu). One wave per dst.
// 4 edges processed concurrently by 16-lane groups (uniform j0 bound; safe).
__global__ __launch_bounds__(256) void gat_agg16(
        const float* __restrict__ H, const float* __restrict__ ssrc,
        const float* __restrict__ sdst, const int* __restrict__ off,
        const int* __restrict__ csr, const float* __restrict__ bias,
        float* __restrict__ out, int Nd) {
    int wid = (blockIdx.x * blockDim.x + threadIdx.x) >> 6;
    int lane = threadIdx.x & 63;
    if (wid >= Nd) return;
    int s0 = off[wid], s1 = off[wid + 1];
    float sd = sdst[wid];

    float mx = -1e30f;
    for (int i = s0 + lane; i < s1; i += WAVE) {
        float l = ssrc[csr[i]] + sd;
        l = (l > 0.f) ? l : 0.2f * l;
        mx = fmaxf(mx, l);
    }
    #pragma unroll
    for (int o = 32; o; o >>= 1) mx = fmaxf(mx, __shfl_xor(mx, o));
    float m = (s1 > s0) ? mx : 0.f;

    float den = 0.f;
    float acc = 0.f;
    int eg = lane >> 4, n = lane & 15;
    for (int chunk = s0; chunk < s1; chunk += WAVE) {
        int i = chunk + lane;
        int si = 0; float w = 0.f;
        if (i < s1) {
            si = csr[i];
            float l = ssrc[si] + sd;
            l = (l > 0.f) ? l : 0.2f * l;
            w = __expf(l - m);
        }
        den += w;
        int cnt = min(WAVE, s1 - chunk);
        for (int j0 = 0; j0 < cnt; j0 += 4) {
            int jj = j0 + eg;
            float wj = __shfl(w, jj & 63);
            int sj = __shfl(si, jj & 63);
            if (jj < cnt) acc += wj * H[(size_t)sj * 16 + n];
        }
    }
    #pragma unroll
    for (int o = 32; o; o >>= 1) den += __shfl_xor(den, o);
    float inv = 1.f / (den + 1e-16f);
    acc += __shfl_xor(acc, 16);
    acc += __shfl_xor(acc, 32);
    if (lane < 16)
        out[(size_t)wid * 16 + n] = acc * inv + bias[n];
}

// ---------------------------------------------------------------------------
// Epilogue
// ---------------------------------------------------------------------------
__global__ void sum_rows16(const float* __restrict__ X, const int* __restrict__ idx,
                           int L, float* __restrict__ accum) {
    __shared__ float red[16][16];
    int f = threadIdx.x & 15, r = threadIdx.x >> 4;
    float acc = 0.f;
    for (int i = blockIdx.x * 16 + r; i < L; i += gridDim.x * 16)
        acc += X[(size_t)idx[i] * 16 + f];
    red[r][f] = acc;
    __syncthreads();
    #pragma unroll
    for (int o = 8; o; o >>= 1) {
        if (r < o) red[r][f] += red[r + o][f];
        __syncthreads();
    }
    if (r == 0) atomicAdd(&accum[f], red[0][f]);
}

__global__ void pred16(const float* __restrict__ XA, const int* __restrict__ sidx,
                       const float* __restrict__ accum, float* __restrict__ pred, int L) {
    int i = blockIdx.x * blockDim.x + threadIdx.x;
    if (i >= L) return;
    const float* row = XA + (size_t)sidx[i] * 16;
    float s = 0.f;
    #pragma unroll
    for (int f = 0; f < 16; ++f) s += row[f] * accum[f];
    pred[i] = s;
}

// ---------------------------------------------------------------------------
extern "C" void kernel_launch(void* const* d_in, const int* in_sizes, int n_in,
                              void* d_out, int out_size, void* d_ws, size_t ws_size,
                              hipStream_t stream) {
    const float* xA = (const float*)d_in[0];
    const float* xB = (const float*)d_in[1];
    const int* ei_ab = (const int*)d_in[2];
    const int* ei_ba = (const int*)d_in[3];
    const int* src_idx = (const int*)d_in[4];
    const int* dst_idx = (const int*)d_in[5];

    const int NAn = in_sizes[0] / 128;   // 50000
    const int NBn = in_sizes[1] / 128;   // 50000
    const int E   = in_sizes[2] / 2;     // 1e6
    const int L   = in_sizes[4];         // 1e5

    const float* Wab[3]  = {(const float*)d_in[6],  (const float*)d_in[14], (const float*)d_in[22]};
    const float* asab[3] = {(const float*)d_in[7],  (const float*)d_in[15], (const float*)d_in[23]};
    const float* adab[3] = {(const float*)d_in[8],  (const float*)d_in[16], (const float*)d_in[24]};
    const float* bab[3]  = {(const float*)d_in[9],  (const float*)d_in[17], (const float*)d_in[25]};
    const float* Wba[3]  = {(const float*)d_in[10], (const float*)d_in[18], (const float*)d_in[26]};
    const float* asba[3] = {(const float*)d_in[11], (const float*)d_in[19], (const float*)d_in[27]};
    const float* adba[3] = {(const float*)d_in[12], (const float*)d_in[20], (const float*)d_in[28]};
    const float* bba[3]  = {(const float*)d_in[13], (const float*)d_in[21], (const float*)d_in[29]};

    float* outp   = (float*)d_out;
    float* pred   = outp;
    float* xa_out = outp + L;
    float* xb_out = outp + L + (size_t)NAn * 16;

    // ---- workspace carve (~138 MB total) ----
    char* p = (char*)d_ws;
    auto alloc = [&](size_t n) { char* r = p; p += (n + 255) & ~(size_t)255; return r; };
    unsigned short* FA0 = (unsigned short*)alloc((size_t)NAn * 256 * 2);
    unsigned short* FB0 = (unsigned short*)alloc((size_t)NBn * 256 * 2);
    unsigned short* FA1 = (unsigned short*)alloc((size_t)NAn * 256 * 2);
    unsigned short* FB1 = (unsigned short*)alloc((size_t)NBn * 256 * 2);
    unsigned short* Hb16 = (unsigned short*)alloc((size_t)NAn * 256 * 2); // reused as fp32 [N][16]
    unsigned short* WT  = (unsigned short*)alloc((size_t)256 * 256 * 2);
    float* ssrc = (float*)alloc((size_t)NAn * 4);
    float* sdst = (float*)alloc((size_t)NAn * 4);
    float* wv   = (float*)alloc(256 * 4);
    int* csr_ab = (int*)alloc((size_t)E * 4);
    int* csr_ba = (int*)alloc((size_t)E * 4);
    int* off_ab = (int*)alloc((size_t)(NBn + 1) * 4);
    int* off_ba = (int*)alloc((size_t)(NAn + 1) * 4);
    int* cnt_ab = (int*)alloc((size_t)NBn * 4);
    int* cur_ab = (int*)alloc((size_t)NBn * 4);
    int* cnt_ba = (int*)alloc((size_t)NAn * 4);
    int* cur_ba = (int*)alloc((size_t)NAn * 4);
    int* csum   = (int*)alloc(1024 * 4);
    int* cbase  = (int*)alloc(1024 * 4);
    float* accum16 = (float*)alloc(16 * 4);
    if ((size_t)(p - (char*)d_ws) > ws_size) return;  // clean bail vs GPU fault

    // ---- CSR build (edges identical across layers: build once per call) ----
    hipMemsetAsync(cnt_ab, 0, (size_t)NBn * 4, stream);
    hipMemsetAsync(cur_ab, 0, (size_t)NBn * 4, stream);
    hipMemsetAsync(cnt_ba, 0, (size_t)NAn * 4, stream);
    hipMemsetAsync(cur_ba, 0, (size_t)NAn * 4, stream);
    int eb = (E + 255) / 256;
    int Cab = (NBn + 255) / 256;     // chunk count (<=1024)
    int Cba = (NAn + 255) / 256;
    hist_kernel<<<eb, 256, 0, stream>>>(ei_ab + E, E, cnt_ab);
    chunk_sum_kernel<<<Cab, 256, 0, stream>>>(cnt_ab, csum, NBn);
    exscan_sums_kernel<<<1, 1024, 0, stream>>>(csum, cbase, Cab, off_ab + NBn);
    chunk_scan_kernel<<<Cab, 256, 0, stream>>>(cnt_ab, cbase, off_ab, NBn);
    fill_kernel<<<eb, 256, 0, stream>>>(ei_ab, ei_ab + E, E, off_ab, cur_ab, csr_ab);
    hist_kernel<<<eb, 256, 0, stream>>>(ei_ba + E, E, cnt_ba);
    chunk_sum_kernel<<<Cba, 256, 0, stream>>>(cnt_ba, csum, NAn);
    exscan_sums_kernel<<<1, 1024, 0, stream>>>(csum, cbase, Cba, off_ba + NAn);
    chunk_scan_kernel<<<Cba, 256, 0, stream>>>(cnt_ba, cbase, off_ba, NAn);
    fill_kernel<<<eb, 256, 0, stream>>>(ei_ba, ei_ba + E, E, off_ba, cur_ba, csr_ba);

    // ---- convert inputs to bf16 (layer-0 features, 128-wide) ----
    cvt_bf16_kernel<<<(NAn * 128 / 4 + 255) / 256, 256, 0, stream>>>(xA, FA0, NAn * 128 / 4);
    cvt_bf16_kernel<<<(NBn * 128 / 4 + 255) / 256, 256, 0, stream>>>(xB, FB0, NBn * 128 / 4);

    // ---- conv with Fout=256 (layers 0,1) ----
    auto conv256 = [&](const unsigned short* xs, const unsigned short* xd,
                       int Ns, int Nd, int Fin,
                       const float* W, const float* a_s, const float* a_d,
                       const float* bias, const int* off, const int* csr,
                       unsigned short* out, bool relu) {
        wt_bf16_kernel<<<(Fin * 256 + 255) / 256, 256, 0, stream>>>(W, WT, Fin, 256);
        dim3 gg((Ns + GBM - 1) / GBM, 256 / GBN);
        gemm_bf16<<<gg, 256, 0, stream>>>(xs, WT, Hb16, Ns, 256, Fin);
        rowdot_bf16<<<(Ns * 64 + 255) / 256, 256, 0, stream>>>(Hb16, a_s, ssrc, Ns, 256);
        rowdot_kernel<<<(Fin * 64 + 255) / 256, 256, 0, stream>>>(W, a_d, wv, Fin, 256);
        rowdot_bf16<<<(Nd * 64 + 255) / 256, 256, 0, stream>>>(xd, wv, sdst, Nd, Fin);
        int ab = (Nd + 3) / 4;
        if (relu)
            gat_agg256<true><<<ab, 256, 0, stream>>>(Hb16, ssrc, sdst, off, csr, bias, out, Nd);
        else
            gat_agg256<false><<<ab, 256, 0, stream>>>(Hb16, ssrc, sdst, off, csr, bias, out, Nd);
    };

    // ---- conv with Fout=16 (layer 2; Fin=256, fp32 H and output) ----
    auto conv16 = [&](const unsigned short* xs, const unsigned short* xd,
                      int Ns, int Nd,
                      const float* W, const float* a_s, const float* a_d,
                      const float* bias, const int* off, const int* csr,
                      float* out) {
        float* Hb32 = (float*)Hb16;
        gemm_bf16_n16<<<(Ns + 3) / 4, 256, 0, stream>>>(xs, W, Hb32, Ns);
        rowdot_kernel<<<(Ns * 64 + 255) / 256, 256, 0, stream>>>(Hb32, a_s, ssrc, Ns, 16);
        rowdot_kernel<<<(256 * 64 + 255) / 256, 256, 0, stream>>>(W, a_d, wv, 256, 16);
        rowdot_bf16<<<(Nd * 64 + 255) / 256, 256, 0, stream>>>(xd, wv, sdst, Nd, 256);
        gat_agg16<<<(Nd + 3) / 4, 256, 0, stream>>>(Hb32, ssrc, sdst, off, csr, bias, out, Nd);
    };

    // ---- 3 layers (ping-pong: FA0/FB0 <-> FA1/FB1) ----
    conv256(FA0, FB0, NAn, NBn, 128, Wab[0], asab[0], adab[0], bab[0], off_ab, csr_ab, FB1, true);
    conv256(FB0, FA0, NBn, NAn, 128, Wba[0], asba[0], adba[0], bba[0], off_ba, csr_ba, FA1, true);
    conv256(FA1, FB1, NAn, NBn, 256, Wab[1], asab[1], adab[1], bab[1], off_ab, csr_ab, FB0, true);
    conv256(FB1, FA1, NBn, NAn, 256, Wba[1], asba[1], adba[1], bba[1], off_ba, csr_ba, FA0, true);
    conv16(FA0, FB0, NAn, NBn, Wab[2], asab[2], adab[2], bab[2], off_ab, csr_ab, xb_out);
    conv16(FB0, FA0, NBn, NAn, Wba[2], asba[2], adba[2], bba[2], off_ba, csr_ba, xa_out);

    // ---- epilogue ----
    hipMemsetAsync(accum16, 0, 16 * 4, stream);
    sum_rows16<<<128, 256, 0, stream>>>(xb_out, dst_idx, L, accum16);
    pred16<<<(L + 255) / 256, 256, 0, stream>>>(xa_out, src_idx, accum16, pred, L);
}